// Round 1
// baseline (1329.571 us; speedup 1.0000x reference)
//
#include <hip/hip_runtime.h>
#include <math.h>

#define N_PTS 16384
#define NWIN  512
#define WIN   32
#define DIMC  96
#define HEADS 6
#define HD    16
#define MLP   384

// ---------------- kernel 0: min over xyz per axis ----------------
__global__ void k_min(const float* __restrict__ xyz, float* __restrict__ fmin) {
    __shared__ float s0[256], s1[256], s2[256];
    int t = threadIdx.x;
    float m0 = 1e30f, m1 = 1e30f, m2 = 1e30f;
    for (int n = t; n < N_PTS; n += 256) {
        m0 = fminf(m0, xyz[n * 3 + 0]);
        m1 = fminf(m1, xyz[n * 3 + 1]);
        m2 = fminf(m2, xyz[n * 3 + 2]);
    }
    s0[t] = m0; s1[t] = m1; s2[t] = m2;
    __syncthreads();
    for (int off = 128; off > 0; off >>= 1) {
        if (t < off) {
            s0[t] = fminf(s0[t], s0[t + off]);
            s1[t] = fminf(s1[t], s1[t + off]);
            s2[t] = fminf(s2[t], s2[t + off]);
        }
        __syncthreads();
    }
    if (t == 0) { fmin[0] = s0[0]; fmin[1] = s1[0]; fmin[2] = s2[0]; }
}

// ---------------- kernel 1: quantized coords ----------------
__global__ void k_xq(const float* __restrict__ xyz, const float* __restrict__ fmin,
                     const float* __restrict__ shiftp, int* __restrict__ xq) {
    int n = blockIdx.x * 256 + threadIdx.x;
    if (n >= N_PTS) return;
    float sh = shiftp[0];
    #pragma unroll
    for (int a = 0; a < 3; a++) {
        float v = xyz[n * 3 + a] - fmin[a] + sh;
        float m = fmodf(v, 4.0f);
        xq[n * 3 + a] = (int)floorf(m * 4.0f);  // /0.25 == *4
    }
}

// ---------------- layernorm (wave per row, 4 rows/block) ----------------
__global__ void k_ln(const float* __restrict__ x, const float* __restrict__ w,
                     const float* __restrict__ b, float* __restrict__ y) {
    int wv = threadIdx.x >> 6;
    int lane = threadIdx.x & 63;
    int row = blockIdx.x * 4 + wv;
    if (row >= N_PTS) return;
    const float* xr = x + row * DIMC;
    float x1 = xr[lane];
    float x2 = (lane < 32) ? xr[64 + lane] : 0.0f;
    float sum = x1 + x2;
    #pragma unroll
    for (int o = 32; o > 0; o >>= 1) sum += __shfl_xor(sum, o);
    float mu = sum * (1.0f / 96.0f);
    float d1 = x1 - mu;
    float d2 = (lane < 32) ? (x2 - mu) : 0.0f;
    float sq = d1 * d1 + d2 * d2;
    #pragma unroll
    for (int o = 32; o > 0; o >>= 1) sq += __shfl_xor(sq, o);
    float inv = rsqrtf(sq * (1.0f / 96.0f) + 1e-5f);
    y[row * DIMC + lane] = d1 * inv * w[lane] + b[lane];
    if (lane < 32) y[row * DIMC + 64 + lane] = d2 * inv * w[64 + lane] + b[64 + lane];
}

// ---------------- qkv gemm (naive, 1 thread / output elem) ----------------
__global__ void k_qkv(const float* __restrict__ xh, const float* __restrict__ wqkv,
                      const float* __restrict__ bqkv, float* __restrict__ qb,
                      float* __restrict__ kb, float* __restrict__ vb) {
    long gid = (long)blockIdx.x * 256 + threadIdx.x;
    if (gid >= (long)N_PTS * 288) return;
    int i = (int)(gid / 288), j = (int)(gid % 288);
    const float* xr = xh + i * DIMC;
    const float* wr = wqkv + j * DIMC;
    float acc = bqkv[j];
    for (int c = 0; c < DIMC; c++) acc += xr[c] * wr[c];
    if (j < 96)        qb[i * DIMC + j]        = acc * 0.25f;   // scale = HD^-0.5
    else if (j < 192)  kb[i * DIMC + (j - 96)] = acc;
    else               vb[i * DIMC + (j - 192)] = acc;
}

// ---------------- attention: 1 block / window ----------------
__global__ __launch_bounds__(192) void k_attn(
    const float* __restrict__ qb, const float* __restrict__ kb,
    const float* __restrict__ vb, const int* __restrict__ xq,
    const float* __restrict__ table, float* __restrict__ outb) {
    __shared__ float Ks[WIN * DIMC];
    __shared__ float Vs[WIN * DIMC];
    __shared__ int XQ[WIN][3];
    int w = blockIdx.x;
    int tid = threadIdx.x;
    int base = w * WIN;
    for (int idx = tid; idx < WIN * DIMC; idx += 192) {
        Ks[idx] = kb[base * DIMC + idx];
        Vs[idx] = vb[base * DIMC + idx];
    }
    if (tid < WIN * 3) XQ[tid / 3][tid % 3] = xq[base * 3 + tid];
    __syncthreads();

    int h = tid / WIN, il = tid % WIN;
    float q[HD];
    const float* qr = qb + (base + il) * DIMC + h * HD;
    #pragma unroll
    for (int d = 0; d < HD; d++) q[d] = qr[d];
    int r0b = XQ[il][0], r1b = XQ[il][1], r2b = XQ[il][2];

    float attn[WIN];
    for (int j = 0; j < WIN; j++) {
        const float* kr = Ks + j * DIMC + h * HD;
        float s = 0.0f;
        #pragma unroll
        for (int d = 0; d < HD; d++) s += q[d] * kr[d];
        int r0 = r0b - XQ[j][0] + 15;
        int r1 = r1b - XQ[j][1] + 15;
        int r2 = r2b - XQ[j][2] + 15;
        const float* t0 = table + ((long)(r0 * HEADS + h) * HD) * 3 + 0;
        const float* t1 = table + ((long)(r1 * HEADS + h) * HD) * 3 + 1;
        const float* t2 = table + ((long)(r2 * HEADS + h) * HD) * 3 + 2;
        float bs = 0.0f;
        #pragma unroll
        for (int d = 0; d < HD; d++) {
            float t = t0[d * 3] + t1[d * 3] + t2[d * 3];
            bs += q[d] * t;
        }
        attn[j] = s + bs;
    }
    float m = attn[0];
    #pragma unroll
    for (int j = 1; j < WIN; j++) m = fmaxf(m, attn[j]);
    float den = 0.0f;
    #pragma unroll
    for (int j = 0; j < WIN; j++) { attn[j] = expf(attn[j] - m); den += attn[j]; }
    float rden = 1.0f / den;
    float o[HD];
    #pragma unroll
    for (int d = 0; d < HD; d++) o[d] = 0.0f;
    for (int j = 0; j < WIN; j++) {
        float sm = attn[j] * rden;
        const float* vr = Vs + j * DIMC + h * HD;
        #pragma unroll
        for (int d = 0; d < HD; d++) o[d] += sm * vr[d];
    }
    float* orow = outb + (base + il) * DIMC + h * HD;
    #pragma unroll
    for (int d = 0; d < HD; d++) orow[d] = o[d];
}

// ---------------- proj + residual ----------------
__global__ void k_proj(const float* __restrict__ ao, const float* __restrict__ pw,
                       const float* __restrict__ pb, const float* __restrict__ feats,
                       float* __restrict__ f2) {
    int gid = blockIdx.x * 256 + threadIdx.x;
    if (gid >= N_PTS * DIMC) return;
    int i = gid / DIMC, c = gid % DIMC;
    const float* ar = ao + i * DIMC;
    const float* wr = pw + c * DIMC;
    float acc = pb[c];
    for (int k2 = 0; k2 < DIMC; k2++) acc += ar[k2] * wr[k2];
    f2[gid] = feats[gid] + acc;
}

// ---------------- fc1 + exact gelu ----------------
__global__ void k_fc1(const float* __restrict__ xh, const float* __restrict__ w1,
                      const float* __restrict__ b1, float* __restrict__ hb) {
    long gid = (long)blockIdx.x * 256 + threadIdx.x;
    if (gid >= (long)N_PTS * MLP) return;
    int i = (int)(gid / MLP), j = (int)(gid % MLP);
    const float* xr = xh + i * DIMC;
    const float* wr = w1 + j * DIMC;
    float acc = b1[j];
    for (int c = 0; c < DIMC; c++) acc += xr[c] * wr[c];
    hb[gid] = 0.5f * acc * (1.0f + erff(acc * 0.70710678118654752f));
}

// ---------------- fc2 + residual ----------------
__global__ void k_fc2(const float* __restrict__ hb, const float* __restrict__ w2,
                      const float* __restrict__ b2, const float* __restrict__ f2,
                      float* __restrict__ out) {
    int gid = blockIdx.x * 256 + threadIdx.x;
    if (gid >= N_PTS * DIMC) return;
    int i = gid / DIMC, c = gid % DIMC;
    const float* hr = hb + i * MLP;
    const float* wr = w2 + c * MLP;
    float acc = b2[c];
    for (int j = 0; j < MLP; j++) acc += hr[j] * wr[j];
    out[gid] = f2[gid] + acc;
}

extern "C" void kernel_launch(void* const* d_in, const int* in_sizes, int n_in,
                              void* d_out, int out_size, void* d_ws, size_t ws_size,
                              hipStream_t stream) {
    const float* feats  = (const float*)d_in[0];
    const float* xyz    = (const float*)d_in[1];
    // d_in[2..4]: index arrays (structure is fixed: window w attends within itself)
    const float* shiftp = (const float*)d_in[6];
    const float* n1w = (const float*)d_in[7];
    const float* n1b = (const float*)d_in[8];
    const float* qkvw = (const float*)d_in[9];
    const float* qkvb = (const float*)d_in[10];
    const float* table = (const float*)d_in[11];
    const float* projw = (const float*)d_in[12];
    const float* projb = (const float*)d_in[13];
    const float* n2w = (const float*)d_in[14];
    const float* n2b = (const float*)d_in[15];
    const float* fc1w = (const float*)d_in[16];
    const float* fc1b = (const float*)d_in[17];
    const float* fc2w = (const float*)d_in[18];
    const float* fc2b = (const float*)d_in[19];

    char* ws = (char*)d_ws;
    const size_t SZ_ROW = (size_t)N_PTS * DIMC * sizeof(float);   // 6,291,456
    float* fmin   = (float*)(ws + 0);
    int*   xq     = (int*)  (ws + 64);
    float* xhat   = (float*)(ws + 262144);
    float* qb     = (float*)(ws + 262144 + 1 * SZ_ROW);
    float* kb     = (float*)(ws + 262144 + 2 * SZ_ROW);
    float* vb     = (float*)(ws + 262144 + 3 * SZ_ROW);
    float* ao     = (float*)(ws + 262144 + 4 * SZ_ROW);
    float* f2     = (float*)(ws + 262144 + 5 * SZ_ROW);
    float* xhat2  = (float*)(ws + 262144 + 6 * SZ_ROW);
    float* hb     = (float*)(ws + 262144 + 7 * SZ_ROW);           // N*384 floats

    k_min<<<1, 256, 0, stream>>>(xyz, fmin);
    k_xq<<<(N_PTS + 255) / 256, 256, 0, stream>>>(xyz, fmin, shiftp, xq);
    k_ln<<<N_PTS / 4, 256, 0, stream>>>(feats, n1w, n1b, xhat);
    k_qkv<<<(N_PTS * 288 + 255) / 256, 256, 0, stream>>>(xhat, qkvw, qkvb, qb, kb, vb);
    k_attn<<<NWIN, 192, 0, stream>>>(qb, kb, vb, xq, table, ao);
    k_proj<<<(N_PTS * DIMC + 255) / 256, 256, 0, stream>>>(ao, projw, projb, feats, f2);
    k_ln<<<N_PTS / 4, 256, 0, stream>>>(f2, n2w, n2b, xhat2);
    k_fc1<<<(N_PTS * MLP + 255) / 256, 256, 0, stream>>>(xhat2, fc1w, fc1b, hb);
    k_fc2<<<(N_PTS * DIMC + 255) / 256, 256, 0, stream>>>(hb, fc2w, fc2b, f2, (float*)d_out);
}

// Round 2
// 464.129 us; speedup vs baseline: 2.8647x; 2.8647x over previous
//
#include <hip/hip_runtime.h>
#include <math.h>

#define N_PTS 16384
#define NWIN  512
#define WIN   32
#define DIMC  96
#define HEADS 6
#define HD    16
#define MLP   384

// ---------------- kernel 0: min over xyz per axis ----------------
__global__ void k_min(const float* __restrict__ xyz, float* __restrict__ fmin) {
    __shared__ float s0[256], s1[256], s2[256];
    int t = threadIdx.x;
    float m0 = 1e30f, m1 = 1e30f, m2 = 1e30f;
    for (int n = t; n < N_PTS; n += 256) {
        m0 = fminf(m0, xyz[n * 3 + 0]);
        m1 = fminf(m1, xyz[n * 3 + 1]);
        m2 = fminf(m2, xyz[n * 3 + 2]);
    }
    s0[t] = m0; s1[t] = m1; s2[t] = m2;
    __syncthreads();
    for (int off = 128; off > 0; off >>= 1) {
        if (t < off) {
            s0[t] = fminf(s0[t], s0[t + off]);
            s1[t] = fminf(s1[t], s1[t + off]);
            s2[t] = fminf(s2[t], s2[t + off]);
        }
        __syncthreads();
    }
    if (t == 0) { fmin[0] = s0[0]; fmin[1] = s1[0]; fmin[2] = s2[0]; }
}

// ---------------- kernel 1: quantized coords ----------------
__global__ void k_xq(const float* __restrict__ xyz, const float* __restrict__ fmin,
                     const float* __restrict__ shiftp, int* __restrict__ xq) {
    int n = blockIdx.x * 256 + threadIdx.x;
    if (n >= N_PTS) return;
    float sh = shiftp[0];
    #pragma unroll
    for (int a = 0; a < 3; a++) {
        float v = xyz[n * 3 + a] - fmin[a] + sh;
        float m = fmodf(v, 4.0f);
        xq[n * 3 + a] = (int)floorf(m * 4.0f);  // /0.25 == *4
    }
}

// ---------------- layernorm (wave per row, 4 rows/block) ----------------
__global__ void k_ln(const float* __restrict__ x, const float* __restrict__ w,
                     const float* __restrict__ b, float* __restrict__ y) {
    int wv = threadIdx.x >> 6;
    int lane = threadIdx.x & 63;
    int row = blockIdx.x * 4 + wv;
    if (row >= N_PTS) return;
    const float* xr = x + row * DIMC;
    float x1 = xr[lane];
    float x2 = (lane < 32) ? xr[64 + lane] : 0.0f;
    float sum = x1 + x2;
    #pragma unroll
    for (int o = 32; o > 0; o >>= 1) sum += __shfl_xor(sum, o);
    float mu = sum * (1.0f / 96.0f);
    float d1 = x1 - mu;
    float d2 = (lane < 32) ? (x2 - mu) : 0.0f;
    float sq = d1 * d1 + d2 * d2;
    #pragma unroll
    for (int o = 32; o > 0; o >>= 1) sq += __shfl_xor(sq, o);
    float inv = rsqrtf(sq * (1.0f / 96.0f) + 1e-5f);
    y[row * DIMC + lane] = d1 * inv * w[lane] + b[lane];
    if (lane < 32) y[row * DIMC + 64 + lane] = d2 * inv * w[64 + lane] + b[64 + lane];
}

// ---------------- tiled GEMM: C[M,N] = A[M,K] @ B[N,K]^T  + epilogue -------
// BM=64, BN=64, BK=32, 256 threads, 4x4 micro-tile/thread.
// EPI: 0 = qkv split (+bias, q*0.25) ; 1 = proj (+bias+res) ;
//      2 = fc1 (+bias, exact gelu)   ; 3 = fc2 (+bias+res)
template<int NOUT, int K, int EPI>
__global__ __launch_bounds__(256) void k_gemm(
    const float* __restrict__ A, const float* __restrict__ B,
    const float* __restrict__ bias, const float* __restrict__ res,
    float* __restrict__ o0, float* __restrict__ o1, float* __restrict__ o2) {
    __shared__ float As[32][68];
    __shared__ float Bs[32][68];
    const int i0 = blockIdx.x * 64;
    const int j0 = blockIdx.y * 64;
    const int tid = threadIdx.x;
    const int lr = tid >> 3;        // 0..31  (row within tile for loads)
    const int lk = tid & 7;         // 0..7   (float4 slot along k)
    const int ty = tid >> 4;        // 0..15
    const int tx = tid & 15;        // 0..15

    float acc[4][4];
    #pragma unroll
    for (int r = 0; r < 4; r++)
        #pragma unroll
        for (int c = 0; c < 4; c++) acc[r][c] = 0.0f;

    for (int k0 = 0; k0 < K; k0 += 32) {
        // ---- stage A tile (rows i0..i0+63, k k0..k0+31), k-major in LDS
        #pragma unroll
        for (int h = 0; h < 2; h++) {
            int row = lr + h * 32;
            float4 av = *(const float4*)&A[(size_t)(i0 + row) * K + k0 + lk * 4];
            As[lk * 4 + 0][row] = av.x;
            As[lk * 4 + 1][row] = av.y;
            As[lk * 4 + 2][row] = av.z;
            As[lk * 4 + 3][row] = av.w;
        }
        // ---- stage B tile (weight rows j0..j0+63), guarded vs NOUT
        #pragma unroll
        for (int h = 0; h < 2; h++) {
            int j = lr + h * 32;
            float4 bv = make_float4(0.f, 0.f, 0.f, 0.f);
            if (j0 + j < NOUT)
                bv = *(const float4*)&B[(size_t)(j0 + j) * K + k0 + lk * 4];
            Bs[lk * 4 + 0][j] = bv.x;
            Bs[lk * 4 + 1][j] = bv.y;
            Bs[lk * 4 + 2][j] = bv.z;
            Bs[lk * 4 + 3][j] = bv.w;
        }
        __syncthreads();
        #pragma unroll
        for (int kk = 0; kk < 32; kk++) {
            float4 a4 = *(const float4*)&As[kk][ty * 4];
            float4 b4 = *(const float4*)&Bs[kk][tx * 4];
            float ar[4] = {a4.x, a4.y, a4.z, a4.w};
            float br[4] = {b4.x, b4.y, b4.z, b4.w};
            #pragma unroll
            for (int r = 0; r < 4; r++)
                #pragma unroll
                for (int c = 0; c < 4; c++) acc[r][c] += ar[r] * br[c];
        }
        __syncthreads();
    }

    #pragma unroll
    for (int r = 0; r < 4; r++) {
        int row = i0 + ty * 4 + r;
        #pragma unroll
        for (int c = 0; c < 4; c++) {
            int col = j0 + tx * 4 + c;
            if (col >= NOUT) continue;
            float v = acc[r][c] + bias[col];
            if (EPI == 0) {
                if (col < 96)       o0[(size_t)row * 96 + col]        = v * 0.25f;
                else if (col < 192) o1[(size_t)row * 96 + (col - 96)] = v;
                else                o2[(size_t)row * 96 + (col - 192)] = v;
            } else if (EPI == 1) {
                o0[(size_t)row * NOUT + col] = res[(size_t)row * NOUT + col] + v;
            } else if (EPI == 2) {
                o0[(size_t)row * NOUT + col] = 0.5f * v * (1.0f + erff(v * 0.70710678118654752f));
            } else {
                o0[(size_t)row * NOUT + col] = res[(size_t)row * NOUT + col] + v;
            }
        }
    }
}

// ---------------- attention: 1 block / window ----------------
__global__ __launch_bounds__(192) void k_attn(
    const float* __restrict__ qb, const float* __restrict__ kb,
    const float* __restrict__ vb, const int* __restrict__ xq,
    const float* __restrict__ table, float* __restrict__ outb) {
    __shared__ float Ks[WIN * DIMC];
    __shared__ float Vs[WIN * DIMC];
    __shared__ int XQ[WIN][3];
    int w = blockIdx.x;
    int tid = threadIdx.x;
    int base = w * WIN;
    for (int idx = tid; idx < WIN * DIMC; idx += 192) {
        Ks[idx] = kb[base * DIMC + idx];
        Vs[idx] = vb[base * DIMC + idx];
    }
    if (tid < WIN * 3) XQ[tid / 3][tid % 3] = xq[base * 3 + tid];
    __syncthreads();

    int h = tid / WIN, il = tid % WIN;
    float q[HD];
    const float* qr = qb + (base + il) * DIMC + h * HD;
    #pragma unroll
    for (int d = 0; d < HD; d++) q[d] = qr[d];
    int r0b = XQ[il][0], r1b = XQ[il][1], r2b = XQ[il][2];

    float attn[WIN];
    for (int j = 0; j < WIN; j++) {
        const float* kr = Ks + j * DIMC + h * HD;
        float s = 0.0f;
        #pragma unroll
        for (int d = 0; d < HD; d++) s += q[d] * kr[d];
        int r0 = r0b - XQ[j][0] + 15;
        int r1 = r1b - XQ[j][1] + 15;
        int r2 = r2b - XQ[j][2] + 15;
        const float* t0 = table + ((long)(r0 * HEADS + h) * HD) * 3 + 0;
        const float* t1 = table + ((long)(r1 * HEADS + h) * HD) * 3 + 1;
        const float* t2 = table + ((long)(r2 * HEADS + h) * HD) * 3 + 2;
        float bs = 0.0f;
        #pragma unroll
        for (int d = 0; d < HD; d++) {
            float t = t0[d * 3] + t1[d * 3] + t2[d * 3];
            bs += q[d] * t;
        }
        attn[j] = s + bs;
    }
    float m = attn[0];
    #pragma unroll
    for (int j = 1; j < WIN; j++) m = fmaxf(m, attn[j]);
    float den = 0.0f;
    #pragma unroll
    for (int j = 0; j < WIN; j++) { attn[j] = expf(attn[j] - m); den += attn[j]; }
    float rden = 1.0f / den;
    float o[HD];
    #pragma unroll
    for (int d = 0; d < HD; d++) o[d] = 0.0f;
    for (int j = 0; j < WIN; j++) {
        float sm = attn[j] * rden;
        const float* vr = Vs + j * DIMC + h * HD;
        #pragma unroll
        for (int d = 0; d < HD; d++) o[d] += sm * vr[d];
    }
    float* orow = outb + (base + il) * DIMC + h * HD;
    #pragma unroll
    for (int d = 0; d < HD; d++) orow[d] = o[d];
}

extern "C" void kernel_launch(void* const* d_in, const int* in_sizes, int n_in,
                              void* d_out, int out_size, void* d_ws, size_t ws_size,
                              hipStream_t stream) {
    const float* feats  = (const float*)d_in[0];
    const float* xyz    = (const float*)d_in[1];
    const float* shiftp = (const float*)d_in[6];
    const float* n1w = (const float*)d_in[7];
    const float* n1b = (const float*)d_in[8];
    const float* qkvw = (const float*)d_in[9];
    const float* qkvb = (const float*)d_in[10];
    const float* table = (const float*)d_in[11];
    const float* projw = (const float*)d_in[12];
    const float* projb = (const float*)d_in[13];
    const float* n2w = (const float*)d_in[14];
    const float* n2b = (const float*)d_in[15];
    const float* fc1w = (const float*)d_in[16];
    const float* fc1b = (const float*)d_in[17];
    const float* fc2w = (const float*)d_in[18];
    const float* fc2b = (const float*)d_in[19];

    char* ws = (char*)d_ws;
    const size_t SZ_ROW = (size_t)N_PTS * DIMC * sizeof(float);   // 6,291,456
    float* fmin   = (float*)(ws + 0);
    int*   xq     = (int*)  (ws + 64);
    float* xhat   = (float*)(ws + 262144);
    float* qb     = (float*)(ws + 262144 + 1 * SZ_ROW);
    float* kb     = (float*)(ws + 262144 + 2 * SZ_ROW);
    float* vb     = (float*)(ws + 262144 + 3 * SZ_ROW);
    float* ao     = (float*)(ws + 262144 + 4 * SZ_ROW);
    float* f2     = (float*)(ws + 262144 + 5 * SZ_ROW);
    float* xhat2  = (float*)(ws + 262144 + 6 * SZ_ROW);
    float* hb     = (float*)(ws + 262144 + 7 * SZ_ROW);           // N*384 floats

    k_min<<<1, 256, 0, stream>>>(xyz, fmin);
    k_xq<<<(N_PTS + 255) / 256, 256, 0, stream>>>(xyz, fmin, shiftp, xq);
    k_ln<<<N_PTS / 4, 256, 0, stream>>>(feats, n1w, n1b, xhat);

    dim3 gq(N_PTS / 64, (288 + 63) / 64);   // 256 x 5
    k_gemm<288, 96, 0><<<gq, 256, 0, stream>>>(xhat, qkvw, qkvb, nullptr, qb, kb, vb);

    k_attn<<<NWIN, 192, 0, stream>>>(qb, kb, vb, xq, table, ao);

    dim3 gp(N_PTS / 64, (96 + 63) / 64);    // 256 x 2
    k_gemm<96, 96, 1><<<gp, 256, 0, stream>>>(ao, projw, projb, feats, f2, nullptr, nullptr);

    k_ln<<<N_PTS / 4, 256, 0, stream>>>(f2, n2w, n2b, xhat2);

    dim3 g1(N_PTS / 64, (MLP + 63) / 64);   // 256 x 6
    k_gemm<MLP, 96, 2><<<g1, 256, 0, stream>>>(xhat2, fc1w, fc1b, nullptr, hb, nullptr, nullptr);

    dim3 g2(N_PTS / 64, (96 + 63) / 64);    // 256 x 2
    k_gemm<96, MLP, 3><<<g2, 256, 0, stream>>>(hb, fc2w, fc2b, f2, (float*)d_out, nullptr, nullptr);
}

// Round 3
// 262.700 us; speedup vs baseline: 5.0612x; 1.7668x over previous
//
#include <hip/hip_runtime.h>
#include <math.h>

#define N_PTS 16384
#define NWIN  512
#define WIN   32
#define DIMC  96
#define HEADS 6
#define HD    16
#define MLP   384

// ---------------- kernel 0: min over xyz per axis ----------------
__global__ void k_min(const float* __restrict__ xyz, float* __restrict__ fmin) {
    __shared__ float s0[256], s1[256], s2[256];
    int t = threadIdx.x;
    float m0 = 1e30f, m1 = 1e30f, m2 = 1e30f;
    for (int n = t; n < N_PTS; n += 256) {
        m0 = fminf(m0, xyz[n * 3 + 0]);
        m1 = fminf(m1, xyz[n * 3 + 1]);
        m2 = fminf(m2, xyz[n * 3 + 2]);
    }
    s0[t] = m0; s1[t] = m1; s2[t] = m2;
    __syncthreads();
    for (int off = 128; off > 0; off >>= 1) {
        if (t < off) {
            s0[t] = fminf(s0[t], s0[t + off]);
            s1[t] = fminf(s1[t], s1[t + off]);
            s2[t] = fminf(s2[t], s2[t + off]);
        }
        __syncthreads();
    }
    if (t == 0) { fmin[0] = s0[0]; fmin[1] = s1[0]; fmin[2] = s2[0]; }
}

// ---------------- kernel 1: quantized coords ----------------
__global__ void k_xq(const float* __restrict__ xyz, const float* __restrict__ fmin,
                     const float* __restrict__ shiftp, int* __restrict__ xq) {
    int n = blockIdx.x * 256 + threadIdx.x;
    if (n >= N_PTS) return;
    float sh = shiftp[0];
    #pragma unroll
    for (int a = 0; a < 3; a++) {
        float v = xyz[n * 3 + a] - fmin[a] + sh;
        float m = fmodf(v, 4.0f);
        xq[n * 3 + a] = (int)floorf(m * 4.0f);  // /0.25 == *4
    }
}

// ---------------- table transpose: [r][h][d][a] -> [a][r][h][d] ----------
// only rows r=0..30 are reachable (rel in [0,30] since xq in [0,15])
__global__ void k_ttr(const float* __restrict__ table, float* __restrict__ tt) {
    int idx = blockIdx.x * 256 + threadIdx.x;   // idx = (a*31 + r)*96 + hd
    if (idx >= 3 * 31 * 96) return;
    int a = idx / (31 * 96);
    int rest = idx % (31 * 96);
    int r = rest / 96;
    int hd = rest % 96;
    tt[idx] = table[(r * 96 + hd) * 3 + a];
}

// ---------------- layernorm (wave per row, 4 rows/block) ----------------
__global__ void k_ln(const float* __restrict__ x, const float* __restrict__ w,
                     const float* __restrict__ b, float* __restrict__ y) {
    int wv = threadIdx.x >> 6;
    int lane = threadIdx.x & 63;
    int row = blockIdx.x * 4 + wv;
    if (row >= N_PTS) return;
    const float* xr = x + row * DIMC;
    float x1 = xr[lane];
    float x2 = (lane < 32) ? xr[64 + lane] : 0.0f;
    float sum = x1 + x2;
    #pragma unroll
    for (int o = 32; o > 0; o >>= 1) sum += __shfl_xor(sum, o);
    float mu = sum * (1.0f / 96.0f);
    float d1 = x1 - mu;
    float d2 = (lane < 32) ? (x2 - mu) : 0.0f;
    float sq = d1 * d1 + d2 * d2;
    #pragma unroll
    for (int o = 32; o > 0; o >>= 1) sq += __shfl_xor(sq, o);
    float inv = rsqrtf(sq * (1.0f / 96.0f) + 1e-5f);
    y[row * DIMC + lane] = d1 * inv * w[lane] + b[lane];
    if (lane < 32) y[row * DIMC + 64 + lane] = d2 * inv * w[64 + lane] + b[64 + lane];
}

// ---------------- tiled GEMM: C[M,N] = A[M,K] @ B[N,K]^T  + epilogue -------
template<int NOUT, int K, int EPI>
__global__ __launch_bounds__(256) void k_gemm(
    const float* __restrict__ A, const float* __restrict__ B,
    const float* __restrict__ bias, const float* __restrict__ res,
    float* __restrict__ o0, float* __restrict__ o1, float* __restrict__ o2) {
    __shared__ float As[32][68];
    __shared__ float Bs[32][68];
    const int i0 = blockIdx.x * 64;
    const int j0 = blockIdx.y * 64;
    const int tid = threadIdx.x;
    const int lr = tid >> 3;
    const int lk = tid & 7;
    const int ty = tid >> 4;
    const int tx = tid & 15;

    float acc[4][4];
    #pragma unroll
    for (int r = 0; r < 4; r++)
        #pragma unroll
        for (int c = 0; c < 4; c++) acc[r][c] = 0.0f;

    for (int k0 = 0; k0 < K; k0 += 32) {
        #pragma unroll
        for (int h = 0; h < 2; h++) {
            int row = lr + h * 32;
            float4 av = *(const float4*)&A[(size_t)(i0 + row) * K + k0 + lk * 4];
            As[lk * 4 + 0][row] = av.x;
            As[lk * 4 + 1][row] = av.y;
            As[lk * 4 + 2][row] = av.z;
            As[lk * 4 + 3][row] = av.w;
        }
        #pragma unroll
        for (int h = 0; h < 2; h++) {
            int j = lr + h * 32;
            float4 bv = make_float4(0.f, 0.f, 0.f, 0.f);
            if (j0 + j < NOUT)
                bv = *(const float4*)&B[(size_t)(j0 + j) * K + k0 + lk * 4];
            Bs[lk * 4 + 0][j] = bv.x;
            Bs[lk * 4 + 1][j] = bv.y;
            Bs[lk * 4 + 2][j] = bv.z;
            Bs[lk * 4 + 3][j] = bv.w;
        }
        __syncthreads();
        #pragma unroll
        for (int kk = 0; kk < 32; kk++) {
            float4 a4 = *(const float4*)&As[kk][ty * 4];
            float4 b4 = *(const float4*)&Bs[kk][tx * 4];
            float ar[4] = {a4.x, a4.y, a4.z, a4.w};
            float br[4] = {b4.x, b4.y, b4.z, b4.w};
            #pragma unroll
            for (int r = 0; r < 4; r++)
                #pragma unroll
                for (int c = 0; c < 4; c++) acc[r][c] += ar[r] * br[c];
        }
        __syncthreads();
    }

    #pragma unroll
    for (int r = 0; r < 4; r++) {
        int row = i0 + ty * 4 + r;
        #pragma unroll
        for (int c = 0; c < 4; c++) {
            int col = j0 + tx * 4 + c;
            if (col >= NOUT) continue;
            float v = acc[r][c] + bias[col];
            if (EPI == 0) {
                if (col < 96)       o0[(size_t)row * 96 + col]        = v * 0.25f;
                else if (col < 192) o1[(size_t)row * 96 + (col - 96)] = v;
                else                o2[(size_t)row * 96 + (col - 192)] = v;
            } else if (EPI == 1) {
                o0[(size_t)row * NOUT + col] = res[(size_t)row * NOUT + col] + v;
            } else if (EPI == 2) {
                o0[(size_t)row * NOUT + col] = 0.5f * v * (1.0f + erff(v * 0.70710678118654752f));
            } else {
                o0[(size_t)row * NOUT + col] = res[(size_t)row * NOUT + col] + v;
            }
        }
    }
}

// ---------------- attention: 1 block / window, precomputed bias dots -------
// P[i,h,a,v] = q_{i,h} . T_a[xq_i[a]+15-v]  (v = quantized coord of the key)
// bias(i,j)  = sum_a P[i,h,a,xq_j[a]]
__global__ __launch_bounds__(192) void k_attn(
    const float* __restrict__ qb, const float* __restrict__ kb,
    const float* __restrict__ vb, const int* __restrict__ xq,
    const float* __restrict__ tt, float* __restrict__ outb) {
    __shared__ float Ks[WIN * DIMC];          // 12 KB
    __shared__ float Vs[WIN * DIMC];          // 12 KB
    __shared__ float P[WIN * 289];            // ~37 KB, stride 289 -> bank = il
    __shared__ int XQ[WIN][3];
    int w = blockIdx.x;
    int tid = threadIdx.x;
    int base = w * WIN;
    for (int idx = tid; idx < WIN * DIMC; idx += 192) {
        Ks[idx] = kb[base * DIMC + idx];
        Vs[idx] = vb[base * DIMC + idx];
    }
    if (tid < 96) XQ[tid / 3][tid % 3] = xq[base * 3 + tid];
    __syncthreads();

    int h = tid / 32, il = tid & 31;
    float q[HD];
    const float* qr = qb + (size_t)(base + il) * DIMC + h * HD;
    #pragma unroll
    for (int dq = 0; dq < 4; dq++) {
        float4 q4 = *(const float4*)&qr[dq * 4];
        q[dq * 4 + 0] = q4.x; q[dq * 4 + 1] = q4.y;
        q[dq * 4 + 2] = q4.z; q[dq * 4 + 3] = q4.w;
    }
    int xa0 = XQ[il][0], xa1 = XQ[il][1], xa2 = XQ[il][2];
    float* Prow = &P[il * 289 + h * 48];

    // ---- precompute P: table addresses are wave-uniform (broadcast loads)
    #pragma unroll
    for (int a = 0; a < 3; a++) {
        int xa = (a == 0) ? xa0 : ((a == 1) ? xa1 : xa2);
        for (int r = 0; r < 31; r++) {
            const float* trow = tt + ((a * 31 + r) * HEADS + h) * HD;
            float dot = 0.0f;
            #pragma unroll
            for (int dq = 0; dq < 4; dq++) {
                float4 t4 = *(const float4*)&trow[dq * 4];
                dot += q[dq * 4 + 0] * t4.x + q[dq * 4 + 1] * t4.y
                     + q[dq * 4 + 2] * t4.z + q[dq * 4 + 3] * t4.w;
            }
            int v = xa + 15 - r;
            if (v >= 0 && v < 16) Prow[a * 16 + v] = dot;
        }
    }
    // P is thread-private: no barrier needed.

    float attn[WIN];
    #pragma unroll
    for (int j = 0; j < WIN; j++) {
        const float* kr = &Ks[j * DIMC + h * HD];
        float s = 0.0f;
        #pragma unroll
        for (int dq = 0; dq < 4; dq++) {
            float4 k4 = *(const float4*)&kr[dq * 4];
            s += q[dq * 4 + 0] * k4.x + q[dq * 4 + 1] * k4.y
               + q[dq * 4 + 2] * k4.z + q[dq * 4 + 3] * k4.w;
        }
        s += Prow[0 + XQ[j][0]] + Prow[16 + XQ[j][1]] + Prow[32 + XQ[j][2]];
        attn[j] = s;
    }
    float m = attn[0];
    #pragma unroll
    for (int j = 1; j < WIN; j++) m = fmaxf(m, attn[j]);
    float den = 0.0f;
    #pragma unroll
    for (int j = 0; j < WIN; j++) { attn[j] = expf(attn[j] - m); den += attn[j]; }
    float rden = 1.0f / den;
    float o[HD];
    #pragma unroll
    for (int d = 0; d < HD; d++) o[d] = 0.0f;
    #pragma unroll
    for (int j = 0; j < WIN; j++) {
        float sm = attn[j] * rden;
        const float* vr = &Vs[j * DIMC + h * HD];
        #pragma unroll
        for (int d = 0; d < HD; d++) o[d] += sm * vr[d];
    }
    float* orow = outb + (size_t)(base + il) * DIMC + h * HD;
    #pragma unroll
    for (int d = 0; d < HD; d++) orow[d] = o[d];
}

extern "C" void kernel_launch(void* const* d_in, const int* in_sizes, int n_in,
                              void* d_out, int out_size, void* d_ws, size_t ws_size,
                              hipStream_t stream) {
    const float* feats  = (const float*)d_in[0];
    const float* xyz    = (const float*)d_in[1];
    const float* shiftp = (const float*)d_in[6];
    const float* n1w = (const float*)d_in[7];
    const float* n1b = (const float*)d_in[8];
    const float* qkvw = (const float*)d_in[9];
    const float* qkvb = (const float*)d_in[10];
    const float* table = (const float*)d_in[11];
    const float* projw = (const float*)d_in[12];
    const float* projb = (const float*)d_in[13];
    const float* n2w = (const float*)d_in[14];
    const float* n2b = (const float*)d_in[15];
    const float* fc1w = (const float*)d_in[16];
    const float* fc1b = (const float*)d_in[17];
    const float* fc2w = (const float*)d_in[18];
    const float* fc2b = (const float*)d_in[19];

    char* ws = (char*)d_ws;
    const size_t SZ_ROW = (size_t)N_PTS * DIMC * sizeof(float);   // 6,291,456
    float* fmin   = (float*)(ws + 0);
    int*   xq     = (int*)  (ws + 64);             // 196,608 B
    float* tt     = (float*)(ws + 200704);         // 35,712 B (transposed table)
    float* xhat   = (float*)(ws + 262144);
    float* qb     = (float*)(ws + 262144 + 1 * SZ_ROW);
    float* kb     = (float*)(ws + 262144 + 2 * SZ_ROW);
    float* vb     = (float*)(ws + 262144 + 3 * SZ_ROW);
    float* ao     = (float*)(ws + 262144 + 4 * SZ_ROW);
    float* f2     = (float*)(ws + 262144 + 5 * SZ_ROW);
    float* xhat2  = (float*)(ws + 262144 + 6 * SZ_ROW);
    float* hb     = (float*)(ws + 262144 + 7 * SZ_ROW);           // N*384 floats

    k_min<<<1, 256, 0, stream>>>(xyz, fmin);
    k_xq<<<(N_PTS + 255) / 256, 256, 0, stream>>>(xyz, fmin, shiftp, xq);
    k_ttr<<<(3 * 31 * 96 + 255) / 256, 256, 0, stream>>>(table, tt);
    k_ln<<<N_PTS / 4, 256, 0, stream>>>(feats, n1w, n1b, xhat);

    dim3 gq(N_PTS / 64, (288 + 63) / 64);   // 256 x 5
    k_gemm<288, 96, 0><<<gq, 256, 0, stream>>>(xhat, qkvw, qkvb, nullptr, qb, kb, vb);

    k_attn<<<NWIN, 192, 0, stream>>>(qb, kb, vb, xq, tt, ao);

    dim3 gp(N_PTS / 64, (96 + 63) / 64);    // 256 x 2
    k_gemm<96, 96, 1><<<gp, 256, 0, stream>>>(ao, projw, projb, feats, f2, nullptr, nullptr);

    k_ln<<<N_PTS / 4, 256, 0, stream>>>(f2, n2w, n2b, xhat2);

    dim3 g1(N_PTS / 64, (MLP + 63) / 64);   // 256 x 6
    k_gemm<MLP, 96, 2><<<g1, 256, 0, stream>>>(xhat2, fc1w, fc1b, nullptr, hb, nullptr, nullptr);

    dim3 g2(N_PTS / 64, (96 + 63) / 64);    // 256 x 2
    k_gemm<96, MLP, 3><<<g2, 256, 0, stream>>>(hb, fc2w, fc2b, f2, (float*)d_out, nullptr, nullptr);
}

// Round 5
// 227.060 us; speedup vs baseline: 5.8556x; 1.1570x over previous
//
#include <hip/hip_runtime.h>
#include <math.h>

#define N_PTS 16384
#define NWIN  512
#define WIN   32
#define DIMC  96
#define HEADS 6
#define HD    16
#define MLP   384

typedef __attribute__((ext_vector_type(8))) short bf16x8;
typedef __attribute__((ext_vector_type(4))) float f32x4;

__device__ inline ushort f2bf(float x) {
    unsigned u = __builtin_bit_cast(unsigned, x);
    unsigned r = (u + 0x7fffu + ((u >> 16) & 1u)) >> 16;
    return (ushort)r;
}

// ---------------- kernel 0: min over xyz per axis ----------------
__global__ void k_min(const float* __restrict__ xyz, float* __restrict__ fmin) {
    __shared__ float s0[256], s1[256], s2[256];
    int t = threadIdx.x;
    float m0 = 1e30f, m1 = 1e30f, m2 = 1e30f;
    for (int n = t; n < N_PTS; n += 256) {
        m0 = fminf(m0, xyz[n * 3 + 0]);
        m1 = fminf(m1, xyz[n * 3 + 1]);
        m2 = fminf(m2, xyz[n * 3 + 2]);
    }
    s0[t] = m0; s1[t] = m1; s2[t] = m2;
    __syncthreads();
    for (int off = 128; off > 0; off >>= 1) {
        if (t < off) {
            s0[t] = fminf(s0[t], s0[t + off]);
            s1[t] = fminf(s1[t], s1[t + off]);
            s2[t] = fminf(s2[t], s2[t + off]);
        }
        __syncthreads();
    }
    if (t == 0) { fmin[0] = s0[0]; fmin[1] = s1[0]; fmin[2] = s2[0]; }
}

// ---------------- kernel 1: quantized coords ----------------
__global__ void k_xq(const float* __restrict__ xyz, const float* __restrict__ fmin,
                     const float* __restrict__ shiftp, int* __restrict__ xq) {
    int n = blockIdx.x * 256 + threadIdx.x;
    if (n >= N_PTS) return;
    float sh = shiftp[0];
    #pragma unroll
    for (int a = 0; a < 3; a++) {
        float v = xyz[n * 3 + a] - fmin[a] + sh;
        float m = fmodf(v, 4.0f);
        xq[n * 3 + a] = (int)floorf(m * 4.0f);
    }
}

// ---------------- table transpose: [r][h][d][a] -> [a][r][h][d] ----------
__global__ void k_ttr(const float* __restrict__ table, float* __restrict__ tt) {
    int idx = blockIdx.x * 256 + threadIdx.x;
    if (idx >= 3 * 31 * 96) return;
    int a = idx / (31 * 96);
    int rest = idx % (31 * 96);
    int r = rest / 96;
    int hd = rest % 96;
    tt[idx] = table[(r * 96 + hd) * 3 + a];
}

// ---------------- weight pack fp32 -> bf16 ----------------
__global__ void k_pack(const float* __restrict__ qkvw, const float* __restrict__ projw,
                       const float* __restrict__ fc1w, const float* __restrict__ fc2w,
                       ushort* __restrict__ qkvwb, ushort* __restrict__ projwb,
                       ushort* __restrict__ fc1wb, ushort* __restrict__ fc2wb) {
    int i = blockIdx.x * 256 + threadIdx.x;
    if (i < 27648) qkvwb[i] = f2bf(qkvw[i]);
    if (i < 9216)  projwb[i] = f2bf(projw[i]);
    if (i < 36864) { fc1wb[i] = f2bf(fc1w[i]); fc2wb[i] = f2bf(fc2w[i]); }
}

// ---------------- layernorm -> bf16 (wave per row, 4 rows/block) ----------
__global__ void k_ln(const float* __restrict__ x, const float* __restrict__ w,
                     const float* __restrict__ b, ushort* __restrict__ y) {
    int wv = threadIdx.x >> 6;
    int lane = threadIdx.x & 63;
    int row = blockIdx.x * 4 + wv;
    if (row >= N_PTS) return;
    const float* xr = x + (size_t)row * DIMC;
    float x1 = xr[lane];
    float x2 = (lane < 32) ? xr[64 + lane] : 0.0f;
    float sum = x1 + x2;
    #pragma unroll
    for (int o = 32; o > 0; o >>= 1) sum += __shfl_xor(sum, o);
    float mu = sum * (1.0f / 96.0f);
    float d1 = x1 - mu;
    float d2 = (lane < 32) ? (x2 - mu) : 0.0f;
    float sq = d1 * d1 + d2 * d2;
    #pragma unroll
    for (int o = 32; o > 0; o >>= 1) sq += __shfl_xor(sq, o);
    float inv = rsqrtf(sq * (1.0f / 96.0f) + 1e-5f);
    y[(size_t)row * DIMC + lane] = f2bf(d1 * inv * w[lane] + b[lane]);
    if (lane < 32)
        y[(size_t)row * DIMC + 64 + lane] = f2bf(d2 * inv * w[64 + lane] + b[64 + lane]);
}

// ---------------- MFMA GEMM: C[M,NOUT] = A[M,K](bf16) @ W[NOUT,K](bf16)^T --
// grid (M/64, NOUT/16); 256 thr = 4 waves, wave w does rows bx*64+w*16..+16.
// EPI: 0=qkv split(+bias,q*0.25) 1=proj(+bias+res) 2=fc1(+bias,gelu->bf16) 3=fc2(+bias+res)
template<int NOUT, int K, int EPI>
__global__ __launch_bounds__(256) void k_mgemm(
    const ushort* __restrict__ A, const ushort* __restrict__ B,
    const float* __restrict__ bias, const float* __restrict__ res,
    void* __restrict__ o0, float* __restrict__ o1, float* __restrict__ o2) {
    int tid = threadIdx.x;
    int wv = tid >> 6, l = tid & 63;
    int i0 = blockIdx.x * 64 + wv * 16;
    int j0 = blockIdx.y * 16;
    int mrow = l & 15, kgrp = l >> 4;
    const ushort* arow = A + (size_t)(i0 + mrow) * K + kgrp * 8;
    const ushort* brow = B + (size_t)(j0 + mrow) * K + kgrp * 8;
    f32x4 acc = {0.f, 0.f, 0.f, 0.f};
    #pragma unroll
    for (int k0 = 0; k0 < K; k0 += 32) {
        bf16x8 af = *(const bf16x8*)(arow + k0);
        bf16x8 bf = *(const bf16x8*)(brow + k0);
        acc = __builtin_amdgcn_mfma_f32_16x16x32_bf16(af, bf, acc, 0, 0, 0);
    }
    int col = j0 + mrow;           // C col = lane&15
    int rbase = i0 + kgrp * 4;     // C row = (lane>>4)*4 + reg
    float bc = bias[col];
    #pragma unroll
    for (int r = 0; r < 4; r++) {
        int row = rbase + r;
        float v = acc[r] + bc;
        if (EPI == 0) {
            if (col < 96)       ((float*)o0)[(size_t)row * 96 + col] = v * 0.25f;
            else if (col < 192) o1[(size_t)row * 96 + col - 96] = v;
            else                o2[(size_t)row * 96 + col - 192] = v;
        } else if (EPI == 1) {
            ((float*)o0)[(size_t)row * 96 + col] = res[(size_t)row * 96 + col] + v;
        } else if (EPI == 2) {
            float g = 0.5f * v * (1.0f + erff(v * 0.70710678118654752f));
            ((ushort*)o0)[(size_t)row * NOUT + col] = f2bf(g);
        } else {
            ((float*)o0)[(size_t)row * 96 + col] = res[(size_t)row * 96 + col] + v;
        }
    }
}

// ---------------- attention v3: 1 block/window, 384 thr (2 thr per (h,q)) --
// P[h][e][il]: e=a*16+v, P = q_{il,h} . T_a[xa_il[a]+15-v]; bias(i,j)=sum_a P[a*16+xq_j[a]]
__global__ __launch_bounds__(384) void k_attn(
    const float* __restrict__ qb, const float* __restrict__ kb,
    const float* __restrict__ vb, const int* __restrict__ xq,
    const float* __restrict__ tt, ushort* __restrict__ ao) {
    __shared__ float Ks[WIN * DIMC];      // 12 KB
    __shared__ float Vs[WIN * DIMC];      // 12 KB
    __shared__ float P[HEADS][48][33];    // 38 KB
    __shared__ int XQ[WIN * 3];
    int w = blockIdx.x, tid = threadIdx.x;
    int base = w * WIN;
    for (int idx = tid; idx < WIN * DIMC / 4; idx += 384) {
        ((float4*)Ks)[idx] = ((const float4*)(kb + (size_t)base * DIMC))[idx];
        ((float4*)Vs)[idx] = ((const float4*)(vb + (size_t)base * DIMC))[idx];
    }
    if (tid < 96) XQ[tid] = xq[base * 3 + tid];
    __syncthreads();

    int h = tid / 64, lane = tid & 63, sub = lane >> 5, il = lane & 31;
    float q[HD];
    const float* qr = qb + (size_t)(base + il) * DIMC + h * HD;
    #pragma unroll
    for (int d4 = 0; d4 < 4; d4++) {
        float4 t4 = *(const float4*)&qr[d4 * 4];
        q[d4 * 4 + 0] = t4.x; q[d4 * 4 + 1] = t4.y;
        q[d4 * 4 + 2] = t4.z; q[d4 * 4 + 3] = t4.w;
    }
    int xa[3] = {XQ[il * 3 + 0], XQ[il * 3 + 1], XQ[il * 3 + 2]};

    // P precompute: this thread does 24 of the 48 (a,v) entries
    for (int e = sub * 24; e < sub * 24 + 24; e++) {
        int a = e >> 4, v = e & 15;
        int r = xa[a] + 15 - v;           // always in [0,30]
        const float* trow = tt + (size_t)((a * 31 + r) * HEADS + h) * HD;
        float dot = 0.0f;
        #pragma unroll
        for (int d4 = 0; d4 < 4; d4++) {
            float4 t4 = *(const float4*)&trow[d4 * 4];
            dot += q[d4 * 4 + 0] * t4.x + q[d4 * 4 + 1] * t4.y
                 + q[d4 * 4 + 2] * t4.z + q[d4 * 4 + 3] * t4.w;
        }
        P[h][e][il] = dot;
    }
    __syncthreads();

    float att[16];
    int j0 = sub * 16;
    #pragma unroll
    for (int jj = 0; jj < 16; jj++) {
        int j = j0 + jj;
        const float* kr = &Ks[j * DIMC + h * HD];
        float s = 0.0f;
        #pragma unroll
        for (int d4 = 0; d4 < 4; d4++) {
            float4 k4 = *(const float4*)&kr[d4 * 4];
            s += q[d4 * 4 + 0] * k4.x + q[d4 * 4 + 1] * k4.y
               + q[d4 * 4 + 2] * k4.z + q[d4 * 4 + 3] * k4.w;
        }
        s += P[h][0  + XQ[j * 3 + 0]][il]
           + P[h][16 + XQ[j * 3 + 1]][il]
           + P[h][32 + XQ[j * 3 + 2]][il];
        att[jj] = s;
    }
    float m = att[0];
    #pragma unroll
    for (int jj = 1; jj < 16; jj++) m = fmaxf(m, att[jj]);
    m = fmaxf(m, __shfl_xor(m, 32));
    float den = 0.0f;
    #pragma unroll
    for (int jj = 0; jj < 16; jj++) { att[jj] = expf(att[jj] - m); den += att[jj]; }
    den += __shfl_xor(den, 32);
    float rden = 1.0f / den;
    float o[HD];
    #pragma unroll
    for (int d = 0; d < HD; d++) o[d] = 0.0f;
    #pragma unroll
    for (int jj = 0; jj < 16; jj++) {
        float sm = att[jj] * rden;
        const float* vr = &Vs[(j0 + jj) * DIMC + h * HD];
        #pragma unroll
        for (int d = 0; d < HD; d++) o[d] += sm * vr[d];
    }
    #pragma unroll
    for (int d = 0; d < HD; d++) o[d] += __shfl_xor(o[d], 32);
    ushort* orow = ao + (size_t)(base + il) * DIMC + h * HD;
    #pragma unroll
    for (int d = 0; d < 8; d++) orow[sub * 8 + d] = f2bf(o[sub * 8 + d]);
}

extern "C" void kernel_launch(void* const* d_in, const int* in_sizes, int n_in,
                              void* d_out, int out_size, void* d_ws, size_t ws_size,
                              hipStream_t stream) {
    const float* feats  = (const float*)d_in[0];
    const float* xyz    = (const float*)d_in[1];
    const float* shiftp = (const float*)d_in[6];
    const float* n1w = (const float*)d_in[7];
    const float* n1b = (const float*)d_in[8];
    const float* qkvw = (const float*)d_in[9];
    const float* qkvb = (const float*)d_in[10];
    const float* table = (const float*)d_in[11];
    const float* projw = (const float*)d_in[12];
    const float* projb = (const float*)d_in[13];
    const float* n2w = (const float*)d_in[14];
    const float* n2b = (const float*)d_in[15];
    const float* fc1w = (const float*)d_in[16];
    const float* fc1b = (const float*)d_in[17];
    const float* fc2w = (const float*)d_in[18];
    const float* fc2b = (const float*)d_in[19];

    char* ws = (char*)d_ws;
    float*  fmin   = (float*)(ws + 0);
    int*    xq     = (int*)  (ws + 4096);        // 196,608 B
    float*  tt     = (float*)(ws + 200704);      // 35,712 B
    ushort* qkvwb  = (ushort*)(ws + 262144);     // 55,296 B
    ushort* projwb = (ushort*)(ws + 317440);     // 18,432 B
    ushort* fc1wb  = (ushort*)(ws + 335872);     // 73,728 B
    ushort* fc2wb  = (ushort*)(ws + 409600);     // 73,728 B
    ushort* xhat   = (ushort*)(ws + 524288);     // 3,145,728 B
    float*  qb     = (float*)(ws + 4194304);     // 6,291,456 B
    float*  kb     = (float*)(ws + 10485760);
    float*  vb     = (float*)(ws + 16777216);
    ushort* ao     = (ushort*)(ws + 23068672);   // 3,145,728 B
    float*  f2     = (float*)(ws + 26214400);    // 6,291,456 B
    ushort* xhat2  = (ushort*)(ws + 32505856);   // 3,145,728 B
    ushort* hb     = (ushort*)(ws + 35651584);   // 12,582,912 B

    k_min<<<1, 256, 0, stream>>>(xyz, fmin);
    k_xq<<<(N_PTS + 255) / 256, 256, 0, stream>>>(xyz, fmin, shiftp, xq);
    k_ttr<<<(3 * 31 * 96 + 255) / 256, 256, 0, stream>>>(table, tt);
    k_pack<<<144, 256, 0, stream>>>(qkvw, projw, fc1w, fc2w, qkvwb, projwb, fc1wb, fc2wb);
    k_ln<<<N_PTS / 4, 256, 0, stream>>>(feats, n1w, n1b, xhat);

    k_mgemm<288, 96, 0><<<dim3(N_PTS / 64, 18), 256, 0, stream>>>(
        xhat, qkvwb, qkvb, nullptr, qb, kb, vb);

    k_attn<<<NWIN, 384, 0, stream>>>(qb, kb, vb, xq, tt, ao);

    k_mgemm<96, 96, 1><<<dim3(N_PTS / 64, 6), 256, 0, stream>>>(
        ao, projwb, projb, feats, f2, nullptr, nullptr);

    k_ln<<<N_PTS / 4, 256, 0, stream>>>(f2, n2w, n2b, xhat2);

    k_mgemm<384, 96, 2><<<dim3(N_PTS / 64, 24), 256, 0, stream>>>(
        xhat2, fc1wb, fc1b, nullptr, hb, nullptr, nullptr);

    k_mgemm<96, 384, 3><<<dim3(N_PTS / 64, 6), 256, 0, stream>>>(
        hb, fc2wb, fc2b, f2, (float*)d_out, nullptr, nullptr);
}

// Round 6
// 201.946 us; speedup vs baseline: 6.5838x; 1.1244x over previous
//
#include <hip/hip_runtime.h>
#include <math.h>

#define N_PTS 16384
#define NWIN  512
#define WIN   32
#define DIMC  96
#define HEADS 6
#define HD    16
#define MLP   384

typedef __attribute__((ext_vector_type(8))) short bf16x8;
typedef __attribute__((ext_vector_type(8))) unsigned short u16x8;
typedef __attribute__((ext_vector_type(4))) float f32x4;

__device__ inline ushort f2bf(float x) {
    unsigned u = __builtin_bit_cast(unsigned, x);
    unsigned r = (u + 0x7fffu + ((u >> 16) & 1u)) >> 16;
    return (ushort)r;
}
__device__ inline float bf2f(ushort u) {
    unsigned v = ((unsigned)u) << 16;
    return __builtin_bit_cast(float, v);
}

// ---------------- kernel: min over xyz per axis ----------------
__global__ void k_min(const float* __restrict__ xyz, float* __restrict__ fmin) {
    __shared__ float s0[256], s1[256], s2[256];
    int t = threadIdx.x;
    float m0 = 1e30f, m1 = 1e30f, m2 = 1e30f;
    for (int n = t; n < N_PTS; n += 256) {
        m0 = fminf(m0, xyz[n * 3 + 0]);
        m1 = fminf(m1, xyz[n * 3 + 1]);
        m2 = fminf(m2, xyz[n * 3 + 2]);
    }
    s0[t] = m0; s1[t] = m1; s2[t] = m2;
    __syncthreads();
    for (int off = 128; off > 0; off >>= 1) {
        if (t < off) {
            s0[t] = fminf(s0[t], s0[t + off]);
            s1[t] = fminf(s1[t], s1[t + off]);
            s2[t] = fminf(s2[t], s2[t + off]);
        }
        __syncthreads();
    }
    if (t == 0) { fmin[0] = s0[0]; fmin[1] = s1[0]; fmin[2] = s2[0]; }
}

// ---------------- prep: table transpose + weight packs (fused) ------------
__global__ void k_prep(const float* __restrict__ table, float* __restrict__ tt,
                       const float* __restrict__ qkvw, const float* __restrict__ projw,
                       const float* __restrict__ fc1w, const float* __restrict__ fc2w,
                       ushort* __restrict__ qkvwb, ushort* __restrict__ projwb,
                       ushort* __restrict__ fc1wb, ushort* __restrict__ fc2wb) {
    int i = blockIdx.x * 256 + threadIdx.x;
    if (i < 3 * 31 * 96) {
        int a = i / (31 * 96);
        int rest = i % (31 * 96);
        int r = rest / 96;
        int hd = rest % 96;
        tt[i] = table[(r * 96 + hd) * 3 + a];
    }
    if (i < 27648) qkvwb[i] = f2bf(qkvw[i]);
    if (i < 9216)  projwb[i] = f2bf(projw[i]);
    if (i < 36864) { fc1wb[i] = f2bf(fc1w[i]); fc2wb[i] = f2bf(fc2w[i]); }
}

// ---------------- layernorm -> bf16 (wave per row, 4 rows/block) ----------
__global__ void k_ln(const float* __restrict__ x, const float* __restrict__ w,
                     const float* __restrict__ b, ushort* __restrict__ y) {
    int wv = threadIdx.x >> 6;
    int lane = threadIdx.x & 63;
    int row = blockIdx.x * 4 + wv;
    if (row >= N_PTS) return;
    const float* xr = x + (size_t)row * DIMC;
    float x1 = xr[lane];
    float x2 = (lane < 32) ? xr[64 + lane] : 0.0f;
    float sum = x1 + x2;
    #pragma unroll
    for (int o = 32; o > 0; o >>= 1) sum += __shfl_xor(sum, o);
    float mu = sum * (1.0f / 96.0f);
    float d1 = x1 - mu;
    float d2 = (lane < 32) ? (x2 - mu) : 0.0f;
    float sq = d1 * d1 + d2 * d2;
    #pragma unroll
    for (int o = 32; o > 0; o >>= 1) sq += __shfl_xor(sq, o);
    float inv = rsqrtf(sq * (1.0f / 96.0f) + 1e-5f);
    y[(size_t)row * DIMC + lane] = f2bf(d1 * inv * w[lane] + b[lane]);
    if (lane < 32)
        y[(size_t)row * DIMC + 64 + lane] = f2bf(d2 * inv * w[64 + lane] + b[64 + lane]);
}

// ---------------- MFMA GEMM: C = A[M,K](bf16) @ W[NOUT,K](bf16)^T ---------
// grid (M/64, NOUT/96); 4 waves; wave = 16 rows x 96 cols = 6 coltiles.
// EPI: 0=qkv split->bf16 (q*0.25) 1=proj(+bias+res,f32) 2=fc1(gelu->bf16) 3=fc2(+bias+res,f32)
template<int NOUT, int K, int EPI>
__global__ __launch_bounds__(256) void k_mgemm(
    const ushort* __restrict__ A, const ushort* __restrict__ B,
    const float* __restrict__ bias, const float* __restrict__ res,
    void* __restrict__ o0, void* __restrict__ o1, void* __restrict__ o2) {
    const int NK = K / 32;
    int tid = threadIdx.x;
    int wv = tid >> 6, l = tid & 63;
    int i0 = blockIdx.x * 64 + wv * 16;
    int j0 = blockIdx.y * 96;
    int mrow = l & 15, kgrp = l >> 4;

    bf16x8 af[NK];
    const ushort* arow = A + (size_t)(i0 + mrow) * K + kgrp * 8;
    #pragma unroll
    for (int kt = 0; kt < NK; kt++) af[kt] = *(const bf16x8*)(arow + kt * 32);

    int rbase = i0 + kgrp * 4;
    #pragma unroll
    for (int ct = 0; ct < 6; ct++) {
        int j = j0 + ct * 16;
        const ushort* brow = B + (size_t)(j + mrow) * K + kgrp * 8;
        f32x4 acc = {0.f, 0.f, 0.f, 0.f};
        #pragma unroll
        for (int kt = 0; kt < NK; kt++) {
            bf16x8 bf = *(const bf16x8*)(brow + kt * 32);
            acc = __builtin_amdgcn_mfma_f32_16x16x32_bf16(af[kt], bf, acc, 0, 0, 0);
        }
        int col = j + mrow;
        float bc = bias[col];
        #pragma unroll
        for (int r = 0; r < 4; r++) {
            int row = rbase + r;
            float v = acc[r] + bc;
            if (EPI == 0) {
                if (col < 96)       ((ushort*)o0)[(size_t)row * 96 + col] = f2bf(v * 0.25f);
                else if (col < 192) ((ushort*)o1)[(size_t)row * 96 + col - 96] = f2bf(v);
                else                ((ushort*)o2)[(size_t)row * 96 + col - 192] = f2bf(v);
            } else if (EPI == 1) {
                ((float*)o0)[(size_t)row * 96 + col] = res[(size_t)row * 96 + col] + v;
            } else if (EPI == 2) {
                float g = 0.5f * v * (1.0f + erff(v * 0.70710678118654752f));
                ((ushort*)o0)[(size_t)row * NOUT + col] = f2bf(g);
            } else {
                ((float*)o0)[(size_t)row * 96 + col] = res[(size_t)row * 96 + col] + v;
            }
        }
    }
}

// ---------------- bias-dot precompute (+ inline xq) -----------------------
// P2[i][(a*16+v)*6+h] = q_{i,h} . T_a[xq_i[a]+15-v]   (bf16 out)
__global__ __launch_bounds__(256) void k_bias(
    const ushort* __restrict__ qb, const float* __restrict__ tt,
    const float* __restrict__ xyz, const float* __restrict__ fmin,
    const float* __restrict__ shiftp, int* __restrict__ xq,
    ushort* __restrict__ P2) {
    __shared__ float ttl[8928];       // 35.7 KB
    __shared__ float ql[16][96];      // 6 KB
    __shared__ int xql[16][3];
    int tid = threadIdx.x;
    int i0 = blockIdx.x * 16;
    // stage table
    for (int idx = tid; idx < 2232; idx += 256)
        ((float4*)ttl)[idx] = ((const float4*)tt)[idx];
    // stage q (bf16 -> f32)
    if (tid < 192) {
        int i = tid / 12, c8 = tid % 12;
        u16x8 qv = *(const u16x8*)(qb + (size_t)(i0 + i) * 96 + c8 * 8);
        #pragma unroll
        for (int d = 0; d < 8; d++) ql[i][c8 * 8 + d] = bf2f(qv[d]);
    }
    // xq inline (also write to global for reuse)
    if (tid < 48) {
        int i = tid / 3, a = tid % 3;
        float v = xyz[(size_t)(i0 + i) * 3 + a] - fmin[a] + shiftp[0];
        float m = fmodf(v, 4.0f);
        int q = (int)floorf(m * 4.0f);
        xql[i][a] = q;
        xq[(size_t)(i0 + i) * 3 + a] = q;
    }
    __syncthreads();
    for (int idx = tid; idx < 16 * 288; idx += 256) {
        int il = idx / 288, c = idx % 288;
        int e = c / 6, h = c % 6;
        int a = e >> 4, v = e & 15;
        int r = xql[il][a] + 15 - v;          // in [0,30]
        const float* trow = &ttl[((a * 31 + r) * 6 + h) * 16];
        const float* qrow = &ql[il][h * 16];
        float dot = 0.0f;
        #pragma unroll
        for (int d4 = 0; d4 < 4; d4++) {
            float4 t4 = *(const float4*)&trow[d4 * 4];
            float4 q4 = *(const float4*)&qrow[d4 * 4];
            dot += q4.x * t4.x + q4.y * t4.y + q4.z * t4.z + q4.w * t4.w;
        }
        P2[(size_t)(i0 + il) * 288 + c] = f2bf(dot);
    }
}

// ---------------- attention v4: no scattered global loads -----------------
__global__ __launch_bounds__(384) void k_attn(
    const ushort* __restrict__ qb, const ushort* __restrict__ kb,
    const ushort* __restrict__ vb, const int* __restrict__ xq,
    const ushort* __restrict__ P2, ushort* __restrict__ ao) {
    __shared__ float Ksf[WIN * DIMC];     // 12 KB
    __shared__ float Vsf[WIN * DIMC];     // 12 KB
    __shared__ float P2s[WIN * 289];      // 37 KB (289 = 1 mod 32 -> lane-indexed conflict-free)
    __shared__ int XQ[WIN * 3];
    int w = blockIdx.x, tid = threadIdx.x;
    int base = w * WIN;
    // stage K/V (bf16 -> f32): 3072 halfs each, one u16x8 per thread
    {
        int i = tid / 12, c8 = tid % 12;
        u16x8 kv = *(const u16x8*)(kb + (size_t)(base + i) * 96 + c8 * 8);
        u16x8 vv = *(const u16x8*)(vb + (size_t)(base + i) * 96 + c8 * 8);
        #pragma unroll
        for (int d = 0; d < 8; d++) {
            Ksf[i * 96 + c8 * 8 + d] = bf2f(kv[d]);
            Vsf[i * 96 + c8 * 8 + d] = bf2f(vv[d]);
        }
    }
    // stage P2 slice (32x288 bf16 -> f32 padded rows of 289)
    for (int idx = tid; idx < 1152; idx += 384) {
        int i = idx / 36, c8 = idx % 36;
        u16x8 pv = *(const u16x8*)(P2 + (size_t)(base + i) * 288 + c8 * 8);
        #pragma unroll
        for (int d = 0; d < 8; d++) P2s[i * 289 + c8 * 8 + d] = bf2f(pv[d]);
    }
    if (tid < 96) XQ[tid] = xq[(size_t)base * 3 + tid];
    __syncthreads();

    int h = tid >> 6, lane = tid & 63, sub = lane >> 5, il = lane & 31;
    float q[HD];
    {
        const ushort* qr = qb + (size_t)(base + il) * 96 + h * HD;
        u16x8 q0 = *(const u16x8*)qr;
        u16x8 q1 = *(const u16x8*)(qr + 8);
        #pragma unroll
        for (int d = 0; d < 8; d++) { q[d] = bf2f(q0[d]); q[8 + d] = bf2f(q1[d]); }
    }
    const float* Pr = &P2s[il * 289];

    float att[16];
    int j0 = sub * 16;
    #pragma unroll
    for (int jj = 0; jj < 16; jj++) {
        int j = j0 + jj;
        const float* kr = &Ksf[j * DIMC + h * HD];   // half-wave-uniform -> broadcast
        float s = 0.0f;
        #pragma unroll
        for (int d4 = 0; d4 < 4; d4++) {
            float4 k4 = *(const float4*)&kr[d4 * 4];
            s += q[d4 * 4 + 0] * k4.x + q[d4 * 4 + 1] * k4.y
               + q[d4 * 4 + 2] * k4.z + q[d4 * 4 + 3] * k4.w;
        }
        s += Pr[(0  + XQ[j * 3 + 0]) * 6 + h]
           + Pr[(16 + XQ[j * 3 + 1]) * 6 + h]
           + Pr[(32 + XQ[j * 3 + 2]) * 6 + h];
        att[jj] = s;
    }
    float m = att[0];
    #pragma unroll
    for (int jj = 1; jj < 16; jj++) m = fmaxf(m, att[jj]);
    m = fmaxf(m, __shfl_xor(m, 32));
    float den = 0.0f;
    #pragma unroll
    for (int jj = 0; jj < 16; jj++) { att[jj] = expf(att[jj] - m); den += att[jj]; }
    den += __shfl_xor(den, 32);
    float rden = 1.0f / den;
    float o[HD];
    #pragma unroll
    for (int d = 0; d < HD; d++) o[d] = 0.0f;
    #pragma unroll
    for (int jj = 0; jj < 16; jj++) {
        float sm = att[jj] * rden;
        const float* vr = &Vsf[(j0 + jj) * DIMC + h * HD];
        #pragma unroll
        for (int d = 0; d < HD; d++) o[d] += sm * vr[d];
    }
    #pragma unroll
    for (int d = 0; d < HD; d++) o[d] += __shfl_xor(o[d], 32);
    // store this thread's 8 outputs as one 16B bf16x8
    bf16x8 o8;
    #pragma unroll
    for (int d = 0; d < 8; d++) o8[d] = (short)f2bf(o[sub * 8 + d]);
    *(bf16x8*)(ao + (size_t)(base + il) * 96 + h * HD + sub * 8) = o8;
}

extern "C" void kernel_launch(void* const* d_in, const int* in_sizes, int n_in,
                              void* d_out, int out_size, void* d_ws, size_t ws_size,
                              hipStream_t stream) {
    const float* feats  = (const float*)d_in[0];
    const float* xyz    = (const float*)d_in[1];
    const float* shiftp = (const float*)d_in[6];
    const float* n1w = (const float*)d_in[7];
    const float* n1b = (const float*)d_in[8];
    const float* qkvw = (const float*)d_in[9];
    const float* qkvb = (const float*)d_in[10];
    const float* table = (const float*)d_in[11];
    const float* projw = (const float*)d_in[12];
    const float* projb = (const float*)d_in[13];
    const float* n2w = (const float*)d_in[14];
    const float* n2b = (const float*)d_in[15];
    const float* fc1w = (const float*)d_in[16];
    const float* fc1b = (const float*)d_in[17];
    const float* fc2w = (const float*)d_in[18];
    const float* fc2b = (const float*)d_in[19];

    char* ws = (char*)d_ws;
    float*  fmin   = (float*)(ws + 0);
    int*    xq     = (int*)  (ws + 4096);        // 196,608 B
    float*  tt     = (float*)(ws + 200704);      // 35,712 B
    ushort* qkvwb  = (ushort*)(ws + 262144);     // 55,296 B
    ushort* projwb = (ushort*)(ws + 317440);     // 18,432 B
    ushort* fc1wb  = (ushort*)(ws + 335872);     // 73,728 B
    ushort* fc2wb  = (ushort*)(ws + 409600);     // 73,728 B
    ushort* xhat   = (ushort*)(ws + 524288);     // 3,145,728 B
    ushort* qb     = (ushort*)(ws + 4194304);    // 3,145,728 B
    ushort* kb     = (ushort*)(ws + 7340032);    // 3,145,728 B
    ushort* vb     = (ushort*)(ws + 10485760);   // 3,145,728 B
    ushort* ao     = (ushort*)(ws + 13631488);   // 3,145,728 B
    float*  f2     = (float*)(ws + 16777216);    // 6,291,456 B
    ushort* xhat2  = (ushort*)(ws + 23068672);   // 3,145,728 B
    ushort* hb     = (ushort*)(ws + 26214400);   // 12,582,912 B
    ushort* P2     = (ushort*)(ws + 38797312);   // 9,437,184 B

    k_min<<<1, 256, 0, stream>>>(xyz, fmin);
    k_prep<<<144, 256, 0, stream>>>(table, tt, qkvw, projw, fc1w, fc2w,
                                    qkvwb, projwb, fc1wb, fc2wb);
    k_ln<<<N_PTS / 4, 256, 0, stream>>>(feats, n1w, n1b, xhat);

    k_mgemm<288, 96, 0><<<dim3(N_PTS / 64, 3), 256, 0, stream>>>(
        xhat, qkvwb, qkvb, nullptr, qb, kb, vb);

    k_bias<<<N_PTS / 16, 256, 0, stream>>>(qb, tt, xyz, fmin, shiftp, xq, P2);

    k_attn<<<NWIN, 384, 0, stream>>>(qb, kb, vb, xq, P2, ao);

    k_mgemm<96, 96, 1><<<dim3(N_PTS / 64, 1), 256, 0, stream>>>(
        ao, projwb, projb, feats, f2, nullptr, nullptr);

    k_ln<<<N_PTS / 4, 256, 0, stream>>>(f2, n2w, n2b, xhat2);

    k_mgemm<384, 96, 2><<<dim3(N_PTS / 64, 4), 256, 0, stream>>>(
        xhat2, fc1wb, fc1b, nullptr, hb, nullptr, nullptr);

    k_mgemm<96, 384, 3><<<dim3(N_PTS / 64, 1), 256, 0, stream>>>(
        hb, fc2wb, fc2b, f2, d_out, nullptr, nullptr);
}

// Round 8
// 167.685 us; speedup vs baseline: 7.9290x; 1.2043x over previous
//
#include <hip/hip_runtime.h>
#include <math.h>

#define N_PTS 16384
#define NWIN  512

typedef __attribute__((ext_vector_type(8))) short bf16x8;
typedef __attribute__((ext_vector_type(8))) unsigned short u16x8;
typedef __attribute__((ext_vector_type(4))) float f32x4;

__device__ inline ushort f2bf(float x) {
    unsigned u = __builtin_bit_cast(unsigned, x);
    unsigned r = (u + 0x7fffu + ((u >> 16) & 1u)) >> 16;
    return (ushort)r;
}
__device__ inline float bf2f(ushort u) {
    unsigned v = ((unsigned)u) << 16;
    return __builtin_bit_cast(float, v);
}

// ---------------- min over xyz per axis (single block, 1024 thr) ----------
__global__ __launch_bounds__(1024) void k_min(const float* __restrict__ xyz,
                                              float* __restrict__ fmin) {
    __shared__ float s0[1024], s1[1024], s2[1024];
    int t = threadIdx.x;
    float m0 = 1e30f, m1 = 1e30f, m2 = 1e30f;
    for (int f = t; f < 12288; f += 1024) {       // 49152 floats / 4
        float4 v = ((const float4*)xyz)[f];
        int a0 = (4 * f) % 3;
        if (a0 == 0)      { m0 = fminf(m0, fminf(v.x, v.w)); m1 = fminf(m1, v.y); m2 = fminf(m2, v.z); }
        else if (a0 == 1) { m1 = fminf(m1, fminf(v.x, v.w)); m2 = fminf(m2, v.y); m0 = fminf(m0, v.z); }
        else              { m2 = fminf(m2, fminf(v.x, v.w)); m0 = fminf(m0, v.y); m1 = fminf(m1, v.z); }
    }
    s0[t] = m0; s1[t] = m1; s2[t] = m2;
    __syncthreads();
    for (int off = 512; off > 0; off >>= 1) {
        if (t < off) {
            s0[t] = fminf(s0[t], s0[t + off]);
            s1[t] = fminf(s1[t], s1[t + off]);
            s2[t] = fminf(s2[t], s2[t + off]);
        }
        __syncthreads();
    }
    if (t == 0) { fmin[0] = s0[0]; fmin[1] = s1[0]; fmin[2] = s2[0]; }
}

// ---------------- prep: table transpose + weight packs --------------------
__global__ void k_prep(const float* __restrict__ table, float* __restrict__ tt,
                       const float* __restrict__ qkvw, const float* __restrict__ projw,
                       const float* __restrict__ fc1w, const float* __restrict__ fc2w,
                       ushort* __restrict__ qkvwb, ushort* __restrict__ projwb,
                       ushort* __restrict__ fc1wb, ushort* __restrict__ fc2wb) {
    int i = blockIdx.x * 256 + threadIdx.x;
    if (i < 3 * 31 * 96) {
        int a = i / (31 * 96);
        int rest = i % (31 * 96);
        int r = rest / 96;
        int hd = rest % 96;
        tt[i] = table[(r * 96 + hd) * 3 + a];
    }
    if (i < 27648) qkvwb[i] = f2bf(qkvw[i]);
    if (i < 9216)  projwb[i] = f2bf(projw[i]);
    if (i < 36864) { fc1wb[i] = f2bf(fc1w[i]); fc2wb[i] = f2bf(fc2w[i]); }
}

#define MFMA(a, b, c) __builtin_amdgcn_mfma_f32_16x16x32_bf16((a), (b), (c), 0, 0, 0)

// ---------------- megakernel: one block per 32-point window ---------------
__global__ __launch_bounds__(256) void k_mega(
    const float* __restrict__ feats_g, const float* __restrict__ xyz,
    const float* __restrict__ fmin, const float* __restrict__ shiftp,
    const float* __restrict__ n1w, const float* __restrict__ n1b,
    const ushort* __restrict__ qkvwb, const float* __restrict__ qkvb,
    const float* __restrict__ tt,
    const ushort* __restrict__ projwb, const float* __restrict__ projb,
    const float* __restrict__ n2w, const float* __restrict__ n2b,
    const ushort* __restrict__ fc1wb, const float* __restrict__ fc1b,
    const ushort* __restrict__ fc2wb, const float* __restrict__ fc2b,
    float* __restrict__ out)
{
    __shared__ __align__(16) char smem[64768];
    float*  Fe = (float*)(smem);            // [32][97] f32: feats -> f2 (in place)
    ushort* XH = (ushort*)(smem + 12416);   // [32][104] bf16: xhat1 -> attn-out
    float*  Kf = (float*)(smem + 19072);    // [32][100] f32: K
    ushort* Qb = (ushort*)(smem + 31872);   // [32][104] bf16: q -> xhat2
    ushort* Vb = (ushort*)(smem + 38528);   // [32][104] bf16: V
    ushort* Hs = (ushort*)(smem + 38528);   // [32][392] bf16: fc1 out (overlays V+P)
    ushort* Ps = (ushort*)(smem + 45184);   // [192][50] bf16: bias dots
    int*    XQ = (int*)(smem + 64384);      // [32][3]

    const int tid = threadIdx.x;
    const int base = blockIdx.x * 32;
    const int wv = tid >> 6, l = tid & 63;
    const int mrow = l & 15, kgrp = l >> 4;

    // ---- A: load feats (f32) + quantized coords
    {
        const float4* fg = (const float4*)(feats_g + (size_t)base * 96);
        #pragma unroll
        for (int it = 0; it < 3; it++) {
            int f = tid + it * 256;                 // < 768
            float4 v = fg[f];
            int r = f / 24, c = (f % 24) * 4;
            float* d = &Fe[r * 97 + c];
            d[0] = v.x; d[1] = v.y; d[2] = v.z; d[3] = v.w;
        }
        if (tid < 96) {
            int i = tid / 3, a = tid % 3;
            float v = xyz[(size_t)(base + i) * 3 + a] - fmin[a] + shiftp[0];
            XQ[tid] = (int)floorf(fmodf(v, 4.0f) * 4.0f);
        }
    }
    __syncthreads();

    // ---- B: LN1 -> XH (bf16), 8 lanes per row
    {
        int row = tid >> 3, sl = tid & 7;
        const float* xr = &Fe[row * 97];
        float s = 0.f, s2 = 0.f;
        #pragma unroll
        for (int k = 0; k < 12; k++) { float x = xr[sl * 12 + k]; s += x; s2 += x * x; }
        #pragma unroll
        for (int o = 1; o < 8; o <<= 1) { s += __shfl_xor(s, o); s2 += __shfl_xor(s2, o); }
        float mu = s * (1.f / 96.f);
        float inv = rsqrtf(s2 * (1.f / 96.f) - mu * mu + 1e-5f);
        #pragma unroll
        for (int k = 0; k < 12; k++) {
            int c = sl * 12 + k;
            XH[row * 104 + c] = f2bf((xr[c] - mu) * inv * n1w[c] + n1b[c]);
        }
    }
    __syncthreads();

    // ---- C: qkv GEMM (2 rowblocks x 18 coltiles = 36 MFMA tiles)
    {
        for (int t8 = wv; t8 < 36; t8 += 4) {
            int rb = t8 / 18, ct = t8 % 18;
            int row = rb * 16 + mrow;
            bf16x8 a0 = *(const bf16x8*)&XH[row * 104 + kgrp * 8];
            bf16x8 a1 = *(const bf16x8*)&XH[row * 104 + kgrp * 8 + 32];
            bf16x8 a2 = *(const bf16x8*)&XH[row * 104 + kgrp * 8 + 64];
            const ushort* br = qkvwb + (size_t)(ct * 16 + mrow) * 96 + kgrp * 8;
            f32x4 acc = {0.f, 0.f, 0.f, 0.f};
            acc = MFMA(a0, *(const bf16x8*)(br), acc);
            acc = MFMA(a1, *(const bf16x8*)(br + 32), acc);
            acc = MFMA(a2, *(const bf16x8*)(br + 64), acc);
            int col = ct * 16 + mrow;
            float bc = qkvb[col];
            #pragma unroll
            for (int r = 0; r < 4; r++) {
                int rw = rb * 16 + kgrp * 4 + r;
                float v = acc[r] + bc;
                if (ct < 6)       Qb[rw * 104 + col] = f2bf(v * 0.25f);
                else if (ct < 12) Kf[rw * 100 + (col - 96)] = v;
                else              Vb[rw * 104 + (col - 192)] = f2bf(v);
            }
        }
    }
    __syncthreads();

    // ---- D: bias dots (wave-uniform table rows) + attention (threads 0..191)
    if (tid < 192) {
        int h = tid >> 5, i = tid & 31;
        float q[16];
        {
            u16x8 q0 = *(const u16x8*)&Qb[i * 104 + h * 16];
            u16x8 q1 = *(const u16x8*)&Qb[i * 104 + h * 16 + 8];
            #pragma unroll
            for (int d = 0; d < 8; d++) { q[d] = bf2f(q0[d]); q[8 + d] = bf2f(q1[d]); }
        }
        int xa0 = XQ[i * 3], xa1 = XQ[i * 3 + 1], xa2 = XQ[i * 3 + 2];
        ushort* Pr = &Ps[tid * 50];
        #pragma unroll
        for (int a = 0; a < 3; a++) {
            int xa = (a == 0) ? xa0 : (a == 1) ? xa1 : xa2;
            #pragma unroll 4
            for (int r = 0; r < 31; r++) {
                const float* trow = tt + (size_t)((a * 31 + r) * 6 + h) * 16;
                float dot = 0.f;
                #pragma unroll
                for (int d4 = 0; d4 < 4; d4++) {
                    float4 t4 = *(const float4*)&trow[d4 * 4];
                    dot += q[d4 * 4 + 0] * t4.x + q[d4 * 4 + 1] * t4.y
                         + q[d4 * 4 + 2] * t4.z + q[d4 * 4 + 3] * t4.w;
                }
                int v = xa + 15 - r;
                if ((unsigned)v < 16u) Pr[a * 16 + v] = f2bf(dot);
            }
        }
        float att[32];
        #pragma unroll
        for (int j = 0; j < 32; j++) {
            const float* kr = &Kf[j * 100 + h * 16];
            float s = 0.f;
            #pragma unroll
            for (int d4 = 0; d4 < 4; d4++) {
                float4 k4 = *(const float4*)&kr[d4 * 4];
                s += q[d4 * 4 + 0] * k4.x + q[d4 * 4 + 1] * k4.y
                   + q[d4 * 4 + 2] * k4.z + q[d4 * 4 + 3] * k4.w;
            }
            s += bf2f(Pr[0  + XQ[j * 3 + 0]])
               + bf2f(Pr[16 + XQ[j * 3 + 1]])
               + bf2f(Pr[32 + XQ[j * 3 + 2]]);
            att[j] = s;
        }
        float m = att[0];
        #pragma unroll
        for (int j = 1; j < 32; j++) m = fmaxf(m, att[j]);
        float den = 0.f;
        #pragma unroll
        for (int j = 0; j < 32; j++) { att[j] = expf(att[j] - m); den += att[j]; }
        float rden = 1.f / den;
        float o[16];
        #pragma unroll
        for (int d = 0; d < 16; d++) o[d] = 0.f;
        #pragma unroll
        for (int j = 0; j < 32; j++) {
            float sm = att[j] * rden;
            u16x8 v0 = *(const u16x8*)&Vb[j * 104 + h * 16];
            u16x8 v1 = *(const u16x8*)&Vb[j * 104 + h * 16 + 8];
            #pragma unroll
            for (int d = 0; d < 8; d++) {
                o[d]     += sm * bf2f(v0[d]);
                o[8 + d] += sm * bf2f(v1[d]);
            }
        }
        u16x8 o0, o1;
        #pragma unroll
        for (int d = 0; d < 8; d++) { o0[d] = f2bf(o[d]); o1[d] = f2bf(o[8 + d]); }
        *(u16x8*)&XH[i * 104 + h * 16] = o0;        // attn-out overwrites xhat1
        *(u16x8*)&XH[i * 104 + h * 16 + 8] = o1;
    }
    __syncthreads();

    // ---- E: proj + residual, f2 in place over Fe
    {
        for (int t8 = wv; t8 < 12; t8 += 4) {
            int rb = t8 / 6, ct = t8 % 6;
            int row = rb * 16 + mrow;
            bf16x8 a0 = *(const bf16x8*)&XH[row * 104 + kgrp * 8];
            bf16x8 a1 = *(const bf16x8*)&XH[row * 104 + kgrp * 8 + 32];
            bf16x8 a2 = *(const bf16x8*)&XH[row * 104 + kgrp * 8 + 64];
            const ushort* br = projwb + (size_t)(ct * 16 + mrow) * 96 + kgrp * 8;
            f32x4 acc = {0.f, 0.f, 0.f, 0.f};
            acc = MFMA(a0, *(const bf16x8*)(br), acc);
            acc = MFMA(a1, *(const bf16x8*)(br + 32), acc);
            acc = MFMA(a2, *(const bf16x8*)(br + 64), acc);
            int col = ct * 16 + mrow;
            float bc = projb[col];
            #pragma unroll
            for (int r = 0; r < 4; r++) {
                int rw = rb * 16 + kgrp * 4 + r;
                Fe[rw * 97 + col] += acc[r] + bc;   // same lane reads+writes -> safe
            }
        }
    }
    __syncthreads();

    // ---- F: LN2 -> Qb (xhat2, bf16)
    {
        int row = tid >> 3, sl = tid & 7;
        const float* xr = &Fe[row * 97];
        float s = 0.f, s2 = 0.f;
        #pragma unroll
        for (int k = 0; k < 12; k++) { float x = xr[sl * 12 + k]; s += x; s2 += x * x; }
        #pragma unroll
        for (int o = 1; o < 8; o <<= 1) { s += __shfl_xor(s, o); s2 += __shfl_xor(s2, o); }
        float mu = s * (1.f / 96.f);
        float inv = rsqrtf(s2 * (1.f / 96.f) - mu * mu + 1e-5f);
        #pragma unroll
        for (int k = 0; k < 12; k++) {
            int c = sl * 12 + k;
            Qb[row * 104 + c] = f2bf((xr[c] - mu) * inv * n2w[c] + n2b[c]);
        }
    }
    __syncthreads();

    // ---- G: fc1 + exact GELU -> Hs (bf16)
    {
        for (int t8 = wv; t8 < 48; t8 += 4) {
            int rb = t8 / 24, ct = t8 % 24;
            int row = rb * 16 + mrow;
            bf16x8 a0 = *(const bf16x8*)&Qb[row * 104 + kgrp * 8];
            bf16x8 a1 = *(const bf16x8*)&Qb[row * 104 + kgrp * 8 + 32];
            bf16x8 a2 = *(const bf16x8*)&Qb[row * 104 + kgrp * 8 + 64];
            const ushort* br = fc1wb + (size_t)(ct * 16 + mrow) * 96 + kgrp * 8;
            f32x4 acc = {0.f, 0.f, 0.f, 0.f};
            acc = MFMA(a0, *(const bf16x8*)(br), acc);
            acc = MFMA(a1, *(const bf16x8*)(br + 32), acc);
            acc = MFMA(a2, *(const bf16x8*)(br + 64), acc);
            int col = ct * 16 + mrow;
            float bc = fc1b[col];
            #pragma unroll
            for (int r = 0; r < 4; r++) {
                int rw = rb * 16 + kgrp * 4 + r;
                float v = acc[r] + bc;
                float g = 0.5f * v * (1.0f + erff(v * 0.70710678118654752f));
                Hs[rw * 392 + col] = f2bf(g);
            }
        }
    }
    __syncthreads();

    // ---- H: fc2 + residual -> out (f32 global)
    {
        for (int t8 = wv; t8 < 12; t8 += 4) {
            int rb = t8 / 6, ct = t8 % 6;
            int row = rb * 16 + mrow;
            bf16x8 af[12];
            #pragma unroll
            for (int kt = 0; kt < 12; kt++)
                af[kt] = *(const bf16x8*)&Hs[row * 392 + kgrp * 8 + kt * 32];
            const ushort* br = fc2wb + (size_t)(ct * 16 + mrow) * 384 + kgrp * 8;
            f32x4 acc = {0.f, 0.f, 0.f, 0.f};
            #pragma unroll
            for (int kt = 0; kt < 12; kt++)
                acc = MFMA(af[kt], *(const bf16x8*)(br + kt * 32), acc);
            int col = ct * 16 + mrow;
            float bc = fc2b[col];
            #pragma unroll
            for (int r = 0; r < 4; r++) {
                int rw = rb * 16 + kgrp * 4 + r;
                out[(size_t)(base + rw) * 96 + col] = Fe[rw * 97 + col] + acc[r] + bc;
            }
        }
    }
}

extern "C" void kernel_launch(void* const* d_in, const int* in_sizes, int n_in,
                              void* d_out, int out_size, void* d_ws, size_t ws_size,
                              hipStream_t stream) {
    const float* feats  = (const float*)d_in[0];
    const float* xyz    = (const float*)d_in[1];
    const float* shiftp = (const float*)d_in[6];
    const float* n1w = (const float*)d_in[7];
    const float* n1b = (const float*)d_in[8];
    const float* qkvw = (const float*)d_in[9];
    const float* qkvb = (const float*)d_in[10];
    const float* table = (const float*)d_in[11];
    const float* projw = (const float*)d_in[12];
    const float* projb = (const float*)d_in[13];
    const float* n2w = (const float*)d_in[14];
    const float* n2b = (const float*)d_in[15];
    const float* fc1w = (const float*)d_in[16];
    const float* fc1b = (const float*)d_in[17];
    const float* fc2w = (const float*)d_in[18];
    const float* fc2b = (const float*)d_in[19];

    char* ws = (char*)d_ws;
    float*  fmin   = (float*)(ws + 0);
    float*  tt     = (float*)(ws + 200704);      // 35,712 B
    ushort* qkvwb  = (ushort*)(ws + 262144);     // 55,296 B
    ushort* projwb = (ushort*)(ws + 317440);     // 18,432 B
    ushort* fc1wb  = (ushort*)(ws + 335872);     // 73,728 B
    ushort* fc2wb  = (ushort*)(ws + 409600);     // 73,728 B

    k_min<<<1, 1024, 0, stream>>>(xyz, fmin);
    k_prep<<<144, 256, 0, stream>>>(table, tt, qkvw, projw, fc1w, fc2w,
                                    qkvwb, projwb, fc1wb, fc2wb);
    k_mega<<<NWIN, 256, 0, stream>>>(feats, xyz, fmin, shiftp,
                                     n1w, n1b, qkvwb, qkvb, tt,
                                     projwb, projb, n2w, n2b,
                                     fc1wb, fc1b, fc2wb, fc2b, (float*)d_out);
}

// Round 10
// 135.564 us; speedup vs baseline: 9.8077x; 1.2369x over previous
//
#include <hip/hip_runtime.h>
#include <math.h>

#define NWIN 512

typedef __attribute__((ext_vector_type(8))) short bf16x8;
typedef __attribute__((ext_vector_type(8))) unsigned short u16x8;
typedef __attribute__((ext_vector_type(4))) float f32x4;
typedef __attribute__((ext_vector_type(16))) float f32x16;

__device__ inline ushort f2bf(float x) {
    unsigned u = __builtin_bit_cast(unsigned, x);
    unsigned r = (u + 0x7fffu + ((u >> 16) & 1u)) >> 16;
    return (ushort)r;
}
__device__ inline float bf2f(ushort u) {
    unsigned v = ((unsigned)u) << 16;
    return __builtin_bit_cast(float, v);
}

#define MFMA16(a, b, c) __builtin_amdgcn_mfma_f32_16x16x32_bf16((a), (b), (c), 0, 0, 0)
#define MFMA32(a, b, c) __builtin_amdgcn_mfma_f32_32x32x16_bf16((a), (b), (c), 0, 0, 0)

// ---------------- prep: fmin init + table pack (bf16, padded) + weight packs
__global__ void k_prep(const float* __restrict__ table, ushort* __restrict__ ttb,
                       const float* __restrict__ qkvw, const float* __restrict__ projw,
                       const float* __restrict__ fc1w, const float* __restrict__ fc2w,
                       ushort* __restrict__ qkvwb, ushort* __restrict__ projwb,
                       ushort* __restrict__ fc1wb, ushort* __restrict__ fc2wb,
                       unsigned* __restrict__ fminU) {
    int i = blockIdx.x * 256 + threadIdx.x;
    if (i < 3) fminU[i] = 0x7F800000u;     // +inf bits (xyz >= 0)
    if (i < 9216) {                        // ttb[a][r(32, pad31)][h][d]
        int d = i & 15;
        int t = i >> 4;                    // (a*32+r)*6 + h
        int h = t % 6;
        int ar = t / 6;
        int r = ar & 31, a = ar >> 5;
        ttb[i] = (r < 31) ? f2bf(table[(r * 96 + h * 16 + d) * 3 + a]) : (ushort)0;
    }
    if (i < 27648) qkvwb[i] = f2bf(qkvw[i]);
    if (i < 9216)  projwb[i] = f2bf(projw[i]);
    if (i < 36864) { fc1wb[i] = f2bf(fc1w[i]); fc2wb[i] = f2bf(fc2w[i]); }
}

// ---------------- min over xyz: 48 blocks, wave-reduce + atomicMin ---------
__global__ __launch_bounds__(256) void k_min(const float* __restrict__ xyz,
                                             unsigned* __restrict__ fminU) {
    int gid = blockIdx.x * 256 + threadIdx.x;      // 12288 float4s exactly
    float4 v = ((const float4*)xyz)[gid];
    float m0 = 1e30f, m1 = 1e30f, m2 = 1e30f;
    int a0 = (gid * 4) % 3;
    if (a0 == 0)      { m0 = fminf(v.x, v.w); m1 = v.y; m2 = v.z; }
    else if (a0 == 1) { m1 = fminf(v.x, v.w); m2 = v.y; m0 = v.z; }
    else              { m2 = fminf(v.x, v.w); m0 = v.y; m1 = v.z; }
    #pragma unroll
    for (int o = 1; o < 64; o <<= 1) {
        m0 = fminf(m0, __shfl_xor(m0, o));
        m1 = fminf(m1, __shfl_xor(m1, o));
        m2 = fminf(m2, __shfl_xor(m2, o));
    }
    if ((threadIdx.x & 63) == 0) {
        atomicMin(&fminU[0], __float_as_uint(m0));
        atomicMin(&fminU[1], __float_as_uint(m1));
        atomicMin(&fminU[2], __float_as_uint(m2));
    }
}

// ---------------- megakernel v2: MFMA attention, 384 thr (wave = head) -----
__global__ __launch_bounds__(384) void k_mega(
    const float* __restrict__ feats_g, const float* __restrict__ xyz,
    const float* __restrict__ fmin, const float* __restrict__ shiftp,
    const float* __restrict__ n1w, const float* __restrict__ n1b,
    const ushort* __restrict__ qkvwb, const float* __restrict__ qkvb,
    const ushort* __restrict__ ttb,
    const ushort* __restrict__ projwb, const float* __restrict__ projb,
    const float* __restrict__ n2w, const float* __restrict__ n2b,
    const ushort* __restrict__ fc1wb, const float* __restrict__ fc1b,
    const ushort* __restrict__ fc2wb, const float* __restrict__ fc2b,
    float* __restrict__ out)
{
    __shared__ __align__(16) char smem[47232];
    ushort* Qb   = (ushort*)(smem);            // [32][104] q (scaled) -> xhat2
    ushort* XH   = (ushort*)(smem + 6656);     // [32][104] xhat1 -> attn-out
    ushort* Kb   = (ushort*)(smem + 13312);    // [32][104] K
    ushort* Vt   = (ushort*)(smem + 19968);    // [6][16][40] V transposed
    ushort* Ps   = (ushort*)(smem + 27648);    // [192][50] bias dots   (R)
    ushort* Plds = (ushort*)(smem + 27648);    // [6][32][40] P^T       (R)
    float*  Fe   = (float*)(smem + 27648);     // [32][97] f2           (R)
    ushort* Hs   = (ushort*)(smem + 6656);     // [32][200] fc1-out (overlays XH+Kb)
    int*    XQ   = (int*)(smem + 46848);       // [32][3]

    const int tid  = threadIdx.x;
    const int base = blockIdx.x * 32;
    const int wv   = tid >> 6;                 // 0..5  (= head in attn phases)
    const int l    = tid & 63;
    const int mrow = l & 15, kgrp = l >> 4;    // 16x16 frag coords
    const int c32  = l & 31, hi2 = l >> 5;     // 32x32 frag coords

    // ---- A: quantized coords
    if (tid < 96) {
        int i = tid / 3, a = tid % 3;
        float v = xyz[(size_t)(base + i) * 3 + a] - fmin[a] + shiftp[0];
        XQ[tid] = (int)floorf(fmodf(v, 4.0f) * 4.0f);
    }
    // ---- B: LN1 from global -> XH bf16 (threads 0..255, 8 lanes/row)
    if (tid < 256) {
        int row = tid >> 3, sl = tid & 7;
        const float* xr = feats_g + (size_t)(base + row) * 96;
        float s = 0.f, s2 = 0.f;
        float xv[12];
        #pragma unroll
        for (int k = 0; k < 12; k++) { xv[k] = xr[sl * 12 + k]; s += xv[k]; s2 += xv[k] * xv[k]; }
        #pragma unroll
        for (int o = 1; o < 8; o <<= 1) { s += __shfl_xor(s, o); s2 += __shfl_xor(s2, o); }
        float mu = s * (1.f / 96.f);
        float inv = rsqrtf(s2 * (1.f / 96.f) - mu * mu + 1e-5f);
        #pragma unroll
        for (int k = 0; k < 12; k++) {
            int c = sl * 12 + k;
            XH[row * 104 + c] = f2bf((xv[k] - mu) * inv * n1w[c] + n1b[c]);
        }
    }
    __syncthreads();

    // ---- C: qkv GEMM (36 tiles / 6 waves)
    for (int t8 = wv; t8 < 36; t8 += 6) {
        int rb = t8 / 18, ct = t8 % 18;
        int row = rb * 16 + mrow;
        bf16x8 a0 = *(const bf16x8*)&XH[row * 104 + kgrp * 8];
        bf16x8 a1 = *(const bf16x8*)&XH[row * 104 + kgrp * 8 + 32];
        bf16x8 a2 = *(const bf16x8*)&XH[row * 104 + kgrp * 8 + 64];
        const ushort* br = qkvwb + (size_t)(ct * 16 + mrow) * 96 + kgrp * 8;
        f32x4 acc = {0.f, 0.f, 0.f, 0.f};
        acc = MFMA16(a0, *(const bf16x8*)(br), acc);
        acc = MFMA16(a1, *(const bf16x8*)(br + 32), acc);
        acc = MFMA16(a2, *(const bf16x8*)(br + 64), acc);
        int col = ct * 16 + mrow;
        float bc = qkvb[col];
        #pragma unroll
        for (int r = 0; r < 4; r++) {
            int rw = rb * 16 + kgrp * 4 + r;
            float v = acc[r] + bc;
            if (ct < 6)       Qb[rw * 104 + col] = f2bf(v * 0.25f);
            else if (ct < 12) Kb[rw * 104 + (col - 96)] = f2bf(v);
            else {
                Vt[((ct - 12) * 16 + mrow) * 40 + rw] = f2bf(v);
            }
        }
    }
    __syncthreads();

    // ---- D1: bias dots via MFMA32: dots[r(regs)][i(lane)] = T_a[r] . q_i
    {
        const int h = wv, i = c32;
        bf16x8 aq = *(const bf16x8*)&Qb[i * 104 + h * 16 + hi2 * 8];
        int xa0 = XQ[i * 3], xa1 = XQ[i * 3 + 1], xa2 = XQ[i * 3 + 2];
        #pragma unroll
        for (int a = 0; a < 3; a++) {
            int xa = (a == 0) ? xa0 : (a == 1) ? xa1 : xa2;
            bf16x8 bt = *(const bf16x8*)&ttb[(size_t)((a * 32 + c32) * 6 + h) * 16 + hi2 * 8];
            f32x16 dt = {0.f,0.f,0.f,0.f,0.f,0.f,0.f,0.f,0.f,0.f,0.f,0.f,0.f,0.f,0.f,0.f};
            dt = MFMA32(bt, aq, dt);
            ushort* Pr = &Ps[(h * 32 + i) * 50 + a * 16];
            #pragma unroll
            for (int reg = 0; reg < 16; reg++) {
                int r = (reg & 3) + 8 * (reg >> 2) + 4 * hi2;
                int v = xa + 15 - r;
                if ((unsigned)v < 16u) Pr[v] = f2bf(dt[reg]);
            }
        }
    }
    __syncthreads();

    // ---- D2a: QK^T via MFMA32 + bias + softmax (thread-local + xor32)
    float av[16];
    float rden;
    {
        const int h = wv, i = c32;
        bf16x8 aq = *(const bf16x8*)&Qb[i * 104 + h * 16 + hi2 * 8];
        bf16x8 ak = *(const bf16x8*)&Kb[c32 * 104 + h * 16 + hi2 * 8];
        f32x16 att = {0.f,0.f,0.f,0.f,0.f,0.f,0.f,0.f,0.f,0.f,0.f,0.f,0.f,0.f,0.f,0.f};
        att = MFMA32(ak, aq, att);        // C: regs = j (K-row), col = i (Q-row)
        const ushort* Pr = &Ps[(h * 32 + i) * 50];
        float m = -1e30f;
        #pragma unroll
        for (int reg = 0; reg < 16; reg++) {
            int j = (reg & 3) + 8 * (reg >> 2) + 4 * hi2;
            float s = att[reg] + bf2f(Pr[XQ[j * 3]])
                               + bf2f(Pr[16 + XQ[j * 3 + 1]])
                               + bf2f(Pr[32 + XQ[j * 3 + 2]]);
            av[reg] = s;
            m = fmaxf(m, s);
        }
        m = fmaxf(m, __shfl_xor(m, 32));
        float den = 0.f;
        #pragma unroll
        for (int reg = 0; reg < 16; reg++) { av[reg] = expf(av[reg] - m); den += av[reg]; }
        den += __shfl_xor(den, 32);
        rden = 1.f / den;
    }
    __syncthreads();                       // Ps dead -> R becomes Plds

    // ---- D2b: stage P^T, PV via MFMA16
    {
        const int h = wv, i = c32;
        #pragma unroll
        for (int reg = 0; reg < 16; reg++) {
            int j = (reg & 3) + 8 * (reg >> 2) + 4 * hi2;
            Plds[(h * 32 + i) * 40 + j] = f2bf(av[reg] * rden);
        }
    }
    __syncthreads();
    {
        const int h = wv;
        bf16x8 avf = *(const bf16x8*)&Vt[(h * 16 + mrow) * 40 + kgrp * 8];
        bf16x8 bp0 = *(const bf16x8*)&Plds[(h * 32 + mrow) * 40 + kgrp * 8];
        bf16x8 bp1 = *(const bf16x8*)&Plds[(h * 32 + 16 + mrow) * 40 + kgrp * 8];
        f32x4 o0 = {0.f, 0.f, 0.f, 0.f};
        f32x4 o1 = {0.f, 0.f, 0.f, 0.f};
        o0 = MFMA16(avf, bp0, o0);        // C: col = i-in-tile (=mrow-lane), row = d
        o1 = MFMA16(avf, bp1, o1);
        #pragma unroll
        for (int r = 0; r < 4; r++) {
            XH[mrow * 104 + h * 16 + kgrp * 4 + r] = f2bf(o0[r]);
            XH[(16 + mrow) * 104 + h * 16 + kgrp * 4 + r] = f2bf(o1[r]);
        }
    }
    __syncthreads();

    // ---- E: proj + residual (feats from global) -> Fe (f32, in R)
    for (int t8 = wv; t8 < 12; t8 += 6) {
        int rb = t8 / 6, ct = t8 % 6;
        int row = rb * 16 + mrow;
        bf16x8 a0 = *(const bf16x8*)&XH[row * 104 + kgrp * 8];
        bf16x8 a1 = *(const bf16x8*)&XH[row * 104 + kgrp * 8 + 32];
        bf16x8 a2 = *(const bf16x8*)&XH[row * 104 + kgrp * 8 + 64];
        const ushort* br = projwb + (size_t)(ct * 16 + mrow) * 96 + kgrp * 8;
        f32x4 acc = {0.f, 0.f, 0.f, 0.f};
        acc = MFMA16(a0, *(const bf16x8*)(br), acc);
        acc = MFMA16(a1, *(const bf16x8*)(br + 32), acc);
        acc = MFMA16(a2, *(const bf16x8*)(br + 64), acc);
        int col = ct * 16 + mrow;
        float bc = projb[col];
        #pragma unroll
        for (int r = 0; r < 4; r++) {
            int rw = rb * 16 + kgrp * 4 + r;
            Fe[rw * 97 + col] = feats_g[(size_t)(base + rw) * 96 + col] + acc[r] + bc;
        }
    }
    __syncthreads();

    // ---- F: LN2 -> Qb (xhat2, bf16)
    if (tid < 256) {
        int row = tid >> 3, sl = tid & 7;
        const float* xr = &Fe[row * 97];
        float s = 0.f, s2 = 0.f;
        float xv[12];
        #pragma unroll
        for (int k = 0; k < 12; k++) { xv[k] = xr[sl * 12 + k]; s += xv[k]; s2 += xv[k] * xv[k]; }
        #pragma unroll
        for (int o = 1; o < 8; o <<= 1) { s += __shfl_xor(s, o); s2 += __shfl_xor(s2, o); }
        float mu = s * (1.f / 96.f);
        float inv = rsqrtf(s2 * (1.f / 96.f) - mu * mu + 1e-5f);
        #pragma unroll
        for (int k = 0; k < 12; k++) {
            int c = sl * 12 + k;
            Qb[row * 104 + c] = f2bf((xv[k] - mu) * inv * n2w[c] + n2b[c]);
        }
    }

    // ---- G/H: MLP in 2 passes over MLP cols (Hs overlays XH+Kb)
    f32x4 hacc0 = {0.f, 0.f, 0.f, 0.f};
    f32x4 hacc1 = {0.f, 0.f, 0.f, 0.f};
    for (int p = 0; p < 2; p++) {
        __syncthreads();
        for (int t8 = wv; t8 < 24; t8 += 6) {
            int rb = t8 / 12, ct = t8 % 12;
            int row = rb * 16 + mrow;
            bf16x8 a0 = *(const bf16x8*)&Qb[row * 104 + kgrp * 8];
            bf16x8 a1 = *(const bf16x8*)&Qb[row * 104 + kgrp * 8 + 32];
            bf16x8 a2 = *(const bf16x8*)&Qb[row * 104 + kgrp * 8 + 64];
            int colg = p * 192 + ct * 16 + mrow;
            const ushort* br = fc1wb + (size_t)colg * 96 + kgrp * 8;
            f32x4 acc = {0.f, 0.f, 0.f, 0.f};
            acc = MFMA16(a0, *(const bf16x8*)(br), acc);
            acc = MFMA16(a1, *(const bf16x8*)(br + 32), acc);
            acc = MFMA16(a2, *(const bf16x8*)(br + 64), acc);
            float bc = fc1b[colg];
            #pragma unroll
            for (int r = 0; r < 4; r++) {
                int rw = rb * 16 + kgrp * 4 + r;
                float v = acc[r] + bc;
                float g = 0.5f * v * (1.0f + erff(v * 0.70710678118654752f));
                Hs[rw * 200 + ct * 16 + mrow] = f2bf(g);
            }
        }
        __syncthreads();
        #pragma unroll
        for (int tt2 = 0; tt2 < 2; tt2++) {
            int t8 = wv + tt2 * 6;
            int rb = t8 / 6, ct = t8 % 6;
            int row = rb * 16 + mrow;
            f32x4 acc = tt2 ? hacc1 : hacc0;
            #pragma unroll
            for (int kt = 0; kt < 6; kt++) {
                bf16x8 af = *(const bf16x8*)&Hs[row * 200 + kgrp * 8 + kt * 32];
                const ushort* bw = fc2wb + (size_t)(ct * 16 + mrow) * 384 + p * 192 + kgrp * 8 + kt * 32;
                acc = MFMA16(af, *(const bf16x8*)bw, acc);
            }
            if (tt2) hacc1 = acc; else hacc0 = acc;
        }
    }
    // ---- epilogue: out = f2 + fc2 + bias
    #pragma unroll
    for (int tt2 = 0; tt2 < 2; tt2++) {
        int t8 = wv + tt2 * 6;
        int rb = t8 / 6, ct = t8 % 6;
        int col = ct * 16 + mrow;
        f32x4 acc = tt2 ? hacc1 : hacc0;
        float bc = fc2b[col];
        #pragma unroll
        for (int r = 0; r < 4; r++) {
            int rw = rb * 16 + kgrp * 4 + r;
            out[(size_t)(base + rw) * 96 + col] = Fe[rw * 97 + col] + acc[r] + bc;
        }
    }
}

extern "C" void kernel_launch(void* const* d_in, const int* in_sizes, int n_in,
                              void* d_out, int out_size, void* d_ws, size_t ws_size,
                              hipStream_t stream) {
    const float* feats  = (const float*)d_in[0];
    const float* xyz    = (const float*)d_in[1];
    const float* shiftp = (const float*)d_in[6];
    const float* n1w = (const float*)d_in[7];
    const float* n1b = (const float*)d_in[8];
    const float* qkvw = (const float*)d_in[9];
    const float* qkvb = (const float*)d_in[10];
    const float* table = (const float*)d_in[11];
    const float* projw = (const float*)d_in[12];
    const float* projb = (const float*)d_in[13];
    const float* n2w = (const float*)d_in[14];
    const float* n2b = (const float*)d_in[15];
    const float* fc1w = (const float*)d_in[16];
    const float* fc1b = (const float*)d_in[17];
    const float* fc2w = (const float*)d_in[18];
    const float* fc2b = (const float*)d_in[19];

    char* ws = (char*)d_ws;
    unsigned* fminU  = (unsigned*)(ws + 0);
    ushort*   ttb    = (ushort*)(ws + 4096);      // 18,432 B
    ushort*   qkvwb  = (ushort*)(ws + 24576);     // 55,296 B
    ushort*   projwb = (ushort*)(ws + 81920);     // 18,432 B
    ushort*   fc1wb  = (ushort*)(ws + 102400);    // 73,728 B
    ushort*   fc2wb  = (ushort*)(ws + 180224);    // 73,728 B

    k_prep<<<144, 256, 0, stream>>>(table, ttb, qkvw, projw, fc1w, fc2w,
                                    qkvwb, projwb, fc1wb, fc2wb, fminU);
    k_min<<<48, 256, 0, stream>>>(xyz, fminU);
    k_mega<<<NWIN, 384, 0, stream>>>(feats, xyz, (const float*)fminU, shiftp,
                                     n1w, n1b, qkvwb, qkvb, ttb,
                                     projwb, projb, n2w, n2b,
                                     fc1wb, fc1b, fc2wb, fc2b, (float*)d_out);
}

// Round 13
// 133.824 us; speedup vs baseline: 9.9352x; 1.0130x over previous
//
#include <hip/hip_runtime.h>
#include <math.h>

#define NWIN 512

typedef __attribute__((ext_vector_type(8))) short bf16x8;
typedef __attribute__((ext_vector_type(4))) float f32x4;
typedef __attribute__((ext_vector_type(16))) float f32x16;

__device__ inline ushort f2bf(float x) {
    unsigned u = __builtin_bit_cast(unsigned, x);
    unsigned r = (u + 0x7fffu + ((u >> 16) & 1u)) >> 16;
    return (ushort)r;
}
__device__ inline float bf2f(ushort u) {
    unsigned v = ((unsigned)u) << 16;
    return __builtin_bit_cast(float, v);
}

#define MFMA16(a, b, c) __builtin_amdgcn_mfma_f32_16x16x32_bf16((a), (b), (c), 0, 0, 0)
#define MFMA32(a, b, c) __builtin_amdgcn_mfma_f32_32x32x16_bf16((a), (b), (c), 0, 0, 0)

// ---- prep: table pack + weight packs + xyz-min (blocks 0..47)  ----
// fminU pre-initialized to 0x7F7F7F7F via hipMemsetAsync (valid +inf-like for xyz>=0)
__global__ void k_prep(const float* __restrict__ table, ushort* __restrict__ ttb,
                       const float* __restrict__ qkvw, const float* __restrict__ projw,
                       const float* __restrict__ fc1w, const float* __restrict__ fc2w,
                       ushort* __restrict__ qkvwb, ushort* __restrict__ projwb,
                       ushort* __restrict__ fc1wb, ushort* __restrict__ fc2wb,
                       const float* __restrict__ xyz, unsigned* __restrict__ fminU) {
    int i = blockIdx.x * 256 + threadIdx.x;
    if (i < 9216) {                        // ttb[a][r(32, pad31)][h][d]
        int d = i & 15;
        int t = i >> 4;                    // (a*32+r)*6 + h
        int h = t % 6;
        int ar = t / 6;
        int r = ar & 31, a = ar >> 5;
        ttb[i] = (r < 31) ? f2bf(table[(r * 96 + h * 16 + d) * 3 + a]) : (ushort)0;
    }
    if (i < 27648) qkvwb[i] = f2bf(qkvw[i]);
    if (i < 9216)  projwb[i] = f2bf(projw[i]);
    if (i < 36864) { fc1wb[i] = f2bf(fc1w[i]); fc2wb[i] = f2bf(fc2w[i]); }
    if (blockIdx.x < 48) {                 // 48*256 = 12288 float4s = whole xyz
        float4 v = ((const float4*)xyz)[i];
        float m0 = 1e30f, m1 = 1e30f, m2 = 1e30f;
        int a0 = (i * 4) % 3;
        if (a0 == 0)      { m0 = fminf(v.x, v.w); m1 = v.y; m2 = v.z; }
        else if (a0 == 1) { m1 = fminf(v.x, v.w); m2 = v.y; m0 = v.z; }
        else              { m2 = fminf(v.x, v.w); m0 = v.y; m1 = v.z; }
        #pragma unroll
        for (int o = 1; o < 64; o <<= 1) {
            m0 = fminf(m0, __shfl_xor(m0, o));
            m1 = fminf(m1, __shfl_xor(m1, o));
            m2 = fminf(m2, __shfl_xor(m2, o));
        }
        if ((threadIdx.x & 63) == 0) {
            atomicMin(&fminU[0], __float_as_uint(m0));
            atomicMin(&fminU[1], __float_as_uint(m1));
            atomicMin(&fminU[2], __float_as_uint(m2));
        }
    }
}

// ---------------- megakernel v2.2: MFMA attention, 384 thr (wave = head) ---
__global__ __launch_bounds__(384) void k_mega(
    const float* __restrict__ feats_g, const float* __restrict__ xyz,
    const float* __restrict__ fmin, const float* __restrict__ shiftp,
    const float* __restrict__ n1w, const float* __restrict__ n1b,
    const ushort* __restrict__ qkvwb, const float* __restrict__ qkvb,
    const ushort* __restrict__ ttb,
    const ushort* __restrict__ projwb, const float* __restrict__ projb,
    const float* __restrict__ n2w, const float* __restrict__ n2b,
    const ushort* __restrict__ fc1wb, const float* __restrict__ fc1b,
    const ushort* __restrict__ fc2wb, const float* __restrict__ fc2b,
    float* __restrict__ out)
{
    __shared__ __align__(16) char smem[47232];
    ushort* Qb   = (ushort*)(smem);            // [32][104] q (scaled) -> xhat2
    ushort* XH   = (ushort*)(smem + 6656);     // [32][104] xhat1 -> attn-out
    ushort* Kb   = (ushort*)(smem + 13312);    // [32][104] K
    ushort* Vt   = (ushort*)(smem + 19968);    // [6][16][40] V transposed
    ushort* Ps   = (ushort*)(smem + 27648);    // [192][50] bias dots   (R)
    ushort* Plds = (ushort*)(smem + 27648);    // [6][32][40] P^T       (R)
    float*  Fe   = (float*)(smem + 27648);     // [32][97] f2           (R)
    ushort* Hs   = (ushort*)(smem + 6656);     // [32][200] fc1-out (overlays XH+Kb)
    int*    XQ   = (int*)(smem + 46848);       // [32][3]

    const int tid  = threadIdx.x;
    const int base = blockIdx.x * 32;
    const int wv   = tid >> 6;                 // 0..5  (= head in attn phases)
    const int l    = tid & 63;
    const int mrow = l & 15, kgrp = l >> 4;    // 16x16 frag coords
    const int c32  = l & 31, hi2 = l >> 5;     // 32x32 frag coords

    // ---- A: quantized coords
    if (tid < 96) {
        int i = tid / 3, a = tid % 3;
        float v = xyz[(size_t)(base + i) * 3 + a] - fmin[a] + shiftp[0];
        XQ[tid] = (int)floorf(fmodf(v, 4.0f) * 4.0f);
    }
    // ---- B: LN1 from global -> XH bf16 (threads 0..255, 8 lanes/row)
    if (tid < 256) {
        int row = tid >> 3, sl = tid & 7;
        const float* xr = feats_g + (size_t)(base + row) * 96;
        float s = 0.f, s2 = 0.f;
        float xv[12];
        #pragma unroll
        for (int k = 0; k < 12; k++) { xv[k] = xr[sl * 12 + k]; s += xv[k]; s2 += xv[k] * xv[k]; }
        #pragma unroll
        for (int o = 1; o < 8; o <<= 1) { s += __shfl_xor(s, o); s2 += __shfl_xor(s2, o); }
        float mu = s * (1.f / 96.f);
        float inv = rsqrtf(s2 * (1.f / 96.f) - mu * mu + 1e-5f);
        #pragma unroll
        for (int k = 0; k < 12; k++) {
            int c = sl * 12 + k;
            XH[row * 104 + c] = f2bf((xv[k] - mu) * inv * n1w[c] + n1b[c]);
        }
    }
    __syncthreads();

    // ---- C: qkv GEMM (36 tiles / 6 waves)
    for (int t8 = wv; t8 < 36; t8 += 6) {
        int rb = t8 / 18, ct = t8 % 18;
        int row = rb * 16 + mrow;
        bf16x8 a0 = *(const bf16x8*)&XH[row * 104 + kgrp * 8];
        bf16x8 a1 = *(const bf16x8*)&XH[row * 104 + kgrp * 8 + 32];
        bf16x8 a2 = *(const bf16x8*)&XH[row * 104 + kgrp * 8 + 64];
        const ushort* br = qkvwb + (size_t)(ct * 16 + mrow) * 96 + kgrp * 8;
        f32x4 acc = {0.f, 0.f, 0.f, 0.f};
        acc = MFMA16(a0, *(const bf16x8*)(br), acc);
        acc = MFMA16(a1, *(const bf16x8*)(br + 32), acc);
        acc = MFMA16(a2, *(const bf16x8*)(br + 64), acc);
        int col = ct * 16 + mrow;
        float bc = qkvb[col];
        #pragma unroll
        for (int r = 0; r < 4; r++) {
            int rw = rb * 16 + kgrp * 4 + r;
            float v = acc[r] + bc;
            if (ct < 6)       Qb[rw * 104 + col] = f2bf(v * 0.25f);
            else if (ct < 12) Kb[rw * 104 + (col - 96)] = f2bf(v);
            else              Vt[((ct - 12) * 16 + mrow) * 40 + rw] = f2bf(v);
        }
    }
    __syncthreads();

    // ---- D1: bias dots via MFMA32: dots[r(regs)][i(lane)] = T_a[r] . q_i
    {
        const int h = wv, i = c32;
        bf16x8 aq = *(const bf16x8*)&Qb[i * 104 + h * 16 + hi2 * 8];
        int xa0 = XQ[i * 3], xa1 = XQ[i * 3 + 1], xa2 = XQ[i * 3 + 2];
        #pragma unroll
        for (int a = 0; a < 3; a++) {
            int xa = (a == 0) ? xa0 : (a == 1) ? xa1 : xa2;
            bf16x8 bt = *(const bf16x8*)&ttb[(size_t)((a * 32 + c32) * 6 + h) * 16 + hi2 * 8];
            f32x16 dt = {0.f,0.f,0.f,0.f,0.f,0.f,0.f,0.f,0.f,0.f,0.f,0.f,0.f,0.f,0.f,0.f};
            dt = MFMA32(bt, aq, dt);
            ushort* Pr = &Ps[(h * 32 + i) * 50 + a * 16];
            #pragma unroll
            for (int reg = 0; reg < 16; reg++) {
                int r = (reg & 3) + 8 * (reg >> 2) + 4 * hi2;
                int v = xa + 15 - r;
                if ((unsigned)v < 16u) Pr[v] = f2bf(dt[reg]);
            }
        }
    }
    // Race fix (round 11 post-mortem): replays diverged without this barrier —
    // D2a's Pr[XQ[...]] loads observed stale LDS. Keep it.
    __syncthreads();

    // ---- D2a: QK^T via MFMA32 + bias + softmax (thread-local + xor32)
    float av[16];
    float rden;
    {
        const int h = wv, i = c32;
        bf16x8 aq = *(const bf16x8*)&Qb[i * 104 + h * 16 + hi2 * 8];
        bf16x8 ak = *(const bf16x8*)&Kb[c32 * 104 + h * 16 + hi2 * 8];
        f32x16 att = {0.f,0.f,0.f,0.f,0.f,0.f,0.f,0.f,0.f,0.f,0.f,0.f,0.f,0.f,0.f,0.f};
        att = MFMA32(ak, aq, att);        // C: regs = j (K-row), col = i (Q-row)
        const ushort* Pr = &Ps[(h * 32 + i) * 50];
        float m = -1e30f;
        #pragma unroll
        for (int reg = 0; reg < 16; reg++) {
            int j = (reg & 3) + 8 * (reg >> 2) + 4 * hi2;
            float s = att[reg] + bf2f(Pr[XQ[j * 3]])
                               + bf2f(Pr[16 + XQ[j * 3 + 1]])
                               + bf2f(Pr[32 + XQ[j * 3 + 2]]);
            av[reg] = s;
            m = fmaxf(m, s);
        }
        m = fmaxf(m, __shfl_xor(m, 32));
        float den = 0.f;
        #pragma unroll
        for (int reg = 0; reg < 16; reg++) { av[reg] = __expf(av[reg] - m); den += av[reg]; }
        den += __shfl_xor(den, 32);
        rden = 1.f / den;
    }
    __syncthreads();                       // Ps dead -> R becomes Plds

    // ---- D2b: stage P^T, PV via MFMA16
    {
        const int h = wv, i = c32;
        #pragma unroll
        for (int reg = 0; reg < 16; reg++) {
            int j = (reg & 3) + 8 * (reg >> 2) + 4 * hi2;
            Plds[(h * 32 + i) * 40 + j] = f2bf(av[reg] * rden);
        }
    }
    __syncthreads();
    {
        const int h = wv;
        bf16x8 avf = *(const bf16x8*)&Vt[(h * 16 + mrow) * 40 + kgrp * 8];
        bf16x8 bp0 = *(const bf16x8*)&Plds[(h * 32 + mrow) * 40 + kgrp * 8];
        bf16x8 bp1 = *(const bf16x8*)&Plds[(h * 32 + 16 + mrow) * 40 + kgrp * 8];
        f32x4 o0 = {0.f, 0.f, 0.f, 0.f};
        f32x4 o1 = {0.f, 0.f, 0.f, 0.f};
        o0 = MFMA16(avf, bp0, o0);        // C: col = i-in-tile (=mrow-lane), row = d
        o1 = MFMA16(avf, bp1, o1);
        #pragma unroll
        for (int r = 0; r < 4; r++) {
            XH[mrow * 104 + h * 16 + kgrp * 4 + r] = f2bf(o0[r]);
            XH[(16 + mrow) * 104 + h * 16 + kgrp * 4 + r] = f2bf(o1[r]);
        }
    }
    __syncthreads();

    // ---- E: proj + residual (feats from global) -> Fe (f32, in R)
    for (int t8 = wv; t8 < 12; t8 += 6) {
        int rb = t8 / 6, ct = t8 % 6;
        int row = rb * 16 + mrow;
        bf16x8 a0 = *(const bf16x8*)&XH[row * 104 + kgrp * 8];
        bf16x8 a1 = *(const bf16x8*)&XH[row * 104 + kgrp * 8 + 32];
        bf16x8 a2 = *(const bf16x8*)&XH[row * 104 + kgrp * 8 + 64];
        const ushort* br = projwb + (size_t)(ct * 16 + mrow) * 96 + kgrp * 8;
        f32x4 acc = {0.f, 0.f, 0.f, 0.f};
        acc = MFMA16(a0, *(const bf16x8*)(br), acc);
        acc = MFMA16(a1, *(const bf16x8*)(br + 32), acc);
        acc = MFMA16(a2, *(const bf16x8*)(br + 64), acc);
        int col = ct * 16 + mrow;
        float bc = projb[col];
        #pragma unroll
        for (int r = 0; r < 4; r++) {
            int rw = rb * 16 + kgrp * 4 + r;
            Fe[rw * 97 + col] = feats_g[(size_t)(base + rw) * 96 + col] + acc[r] + bc;
        }
    }
    __syncthreads();

    // ---- F: LN2 -> Qb (xhat2, bf16)
    if (tid < 256) {
        int row = tid >> 3, sl = tid & 7;
        const float* xr = &Fe[row * 97];
        float s = 0.f, s2 = 0.f;
        float xv[12];
        #pragma unroll
        for (int k = 0; k < 12; k++) { xv[k] = xr[sl * 12 + k]; s += xv[k]; s2 += xv[k] * xv[k]; }
        #pragma unroll
        for (int o = 1; o < 8; o <<= 1) { s += __shfl_xor(s, o); s2 += __shfl_xor(s2, o); }
        float mu = s * (1.f / 96.f);
        float inv = rsqrtf(s2 * (1.f / 96.f) - mu * mu + 1e-5f);
        #pragma unroll
        for (int k = 0; k < 12; k++) {
            int c = sl * 12 + k;
            Qb[row * 104 + c] = f2bf((xv[k] - mu) * inv * n2w[c] + n2b[c]);
        }
    }

    // ---- G/H: MLP in 2 passes over MLP cols (Hs overlays XH+Kb)
    f32x4 hacc0 = {0.f, 0.f, 0.f, 0.f};
    f32x4 hacc1 = {0.f, 0.f, 0.f, 0.f};
    for (int p = 0; p < 2; p++) {
        __syncthreads();
        for (int t8 = wv; t8 < 24; t8 += 6) {
            int rb = t8 / 12, ct = t8 % 12;
            int row = rb * 16 + mrow;
            bf16x8 a0 = *(const bf16x8*)&Qb[row * 104 + kgrp * 8];
            bf16x8 a1 = *(const bf16x8*)&Qb[row * 104 + kgrp * 8 + 32];
            bf16x8 a2 = *(const bf16x8*)&Qb[row * 104 + kgrp * 8 + 64];
            int colg = p * 192 + ct * 16 + mrow;
            const ushort* br = fc1wb + (size_t)colg * 96 + kgrp * 8;
            f32x4 acc = {0.f, 0.f, 0.f, 0.f};
            acc = MFMA16(a0, *(const bf16x8*)(br), acc);
            acc = MFMA16(a1, *(const bf16x8*)(br + 32), acc);
            acc = MFMA16(a2, *(const bf16x8*)(br + 64), acc);
            float bc = fc1b[colg];
            #pragma unroll
            for (int r = 0; r < 4; r++) {
                int rw = rb * 16 + kgrp * 4 + r;
                float v = acc[r] + bc;
                float g = 0.5f * v * (1.0f + erff(v * 0.70710678118654752f));
                Hs[rw * 200 + ct * 16 + mrow] = f2bf(g);
            }
        }
        __syncthreads();
        #pragma unroll
        for (int tt2 = 0; tt2 < 2; tt2++) {
            int t8 = wv + tt2 * 6;
            int rb = t8 / 6, ct = t8 % 6;
            int row = rb * 16 + mrow;
            f32x4 acc = tt2 ? hacc1 : hacc0;
            #pragma unroll
            for (int kt = 0; kt < 6; kt++) {
                bf16x8 af = *(const bf16x8*)&Hs[row * 200 + kgrp * 8 + kt * 32];
                const ushort* bw = fc2wb + (size_t)(ct * 16 + mrow) * 384 + p * 192 + kgrp * 8 + kt * 32;
                acc = MFMA16(af, *(const bf16x8*)bw, acc);
            }
            if (tt2) hacc1 = acc; else hacc0 = acc;
        }
    }
    // ---- epilogue: out = f2 + fc2 + bias
    #pragma unroll
    for (int tt2 = 0; tt2 < 2; tt2++) {
        int t8 = wv + tt2 * 6;
        int rb = t8 / 6, ct = t8 % 6;
        int col = ct * 16 + mrow;
        f32x4 acc = tt2 ? hacc1 : hacc0;
        float bc = fc2b[col];
        #pragma unroll
        for (int r = 0; r < 4; r++) {
            int rw = rb * 16 + kgrp * 4 + r;
            out[(size_t)(base + rw) * 96 + col] = Fe[rw * 97 + col] + acc[r] + bc;
        }
    }
}

extern "C" void kernel_launch(void* const* d_in, const int* in_sizes, int n_in,
                              void* d_out, int out_size, void* d_ws, size_t ws_size,
                              hipStream_t stream) {
    const float* feats  = (const float*)d_in[0];
    const float* xyz    = (const float*)d_in[1];
    const float* shiftp = (const float*)d_in[6];
    const float* n1w = (const float*)d_in[7];
    const float* n1b = (const float*)d_in[8];
    const float* qkvw = (const float*)d_in[9];
    const float* qkvb = (const float*)d_in[10];
    const float* table = (const float*)d_in[11];
    const float* projw = (const float*)d_in[12];
    const float* projb = (const float*)d_in[13];
    const float* n2w = (const float*)d_in[14];
    const float* n2b = (const float*)d_in[15];
    const float* fc1w = (const float*)d_in[16];
    const float* fc1b = (const float*)d_in[17];
    const float* fc2w = (const float*)d_in[18];
    const float* fc2b = (const float*)d_in[19];

    char* ws = (char*)d_ws;
    unsigned* fminU  = (unsigned*)(ws + 0);
    ushort*   ttb    = (ushort*)(ws + 4096);      // 18,432 B
    ushort*   qkvwb  = (ushort*)(ws + 24576);     // 55,296 B
    ushort*   projwb = (ushort*)(ws + 81920);     // 18,432 B
    ushort*   fc1wb  = (ushort*)(ws + 102400);    // 73,728 B
    ushort*   fc2wb  = (ushort*)(ws + 180224);    // 73,728 B

    // 0x7F7F7F7F as float = 3.4e38 > max xyz; uint-bit atomicMin == float min for x>=0
    hipMemsetAsync(fminU, 0x7F, 12, stream);
    k_prep<<<144, 256, 0, stream>>>(table, ttb, qkvw, projw, fc1w, fc2w,
                                    qkvwb, projwb, fc1wb, fc2wb, xyz, fminU);
    k_mega<<<NWIN, 384, 0, stream>>>(feats, xyz, (const float*)fminU, shiftp,
                                     n1w, n1b, qkvwb, qkvb, ttb,
                                     projwb, projb, n2w, n2b,
                                     fc1wb, fc1b, fc2wb, fc2b, (float*)d_out);
}